// Round 2
// baseline (323.930 us; speedup 1.0000x reference)
//
#include <hip/hip_runtime.h>
#include <math.h>

// ---------------------------------------------------------------------------
// PreLossSampler (N=1024):
//   out = [reg_valid | labels | max_overlaps | gt_assignment]  (4096 float32)
//
// Fast path structure (requires ws_size >= WS_NEEDED):
//   prep2      : reg_valid, labels, wave-optimized bitonic argsort(-labels),
//                gather sorted gt boxes, precompute circumscribed circles,
//                zero sup bitmask / pair counters, init rowmax.
//   cand_kernel: circle-reject test over all pairs (gt x gt sorted, j>i; and
//                pred x gt); ballot-compact qualifying pairs into worklists.
//                Value-preserving: rejected pairs have intersection area 0.
//   evalA      : full rotated-IoU on gt-pair worklist -> suppression bits
//                (atomicOr).
//   nms_seq2   : sequential greedy NMS. Wave 0 lanes redundantly hold the
//                full 1024-bit keep mask in 16 u64 registers (template-
//                unrolled static indices); per visited box one broadcast LDS
//                row read + ANDs of words >= w only (lower words are zero).
//                No shfl in the critical chain.
//   evalB      : full IoU3D on pred x gt worklist (skip non-sampled gt),
//                per-row (max,first-idx) via packed u64 atomicMax.
//   fin        : unpack rowmax -> out[2],out[3].
// ---------------------------------------------------------------------------

#define NB 1024
#define CAP 131072u  // per-list entry cap (~13x expected ~10K)

typedef unsigned long long u64;

__device__ __forceinline__ bool pt_in_box(float px, float py,
        float bx, float by, float bdx, float bdy, float cs, float sn) {
    float dx = px - bx, dy = py - by;
    float lx = dx * cs + dy * sn;
    float ly = dy * cs - dx * sn;
    return (fabsf(lx) <= bdx * 0.5f + 1e-5f) && (fabsf(ly) <= bdy * 0.5f + 1e-5f);
}

// Rotated-rectangle intersection area, replicating the reference's candidate
// construction order; stable ascending sort by atan2 about the centroid of
// valid candidate points; shoelace. Arithmetic identical to the round-1
// kernel that validated at absmax 0.
__device__ float rect_inter_area(
        float ax, float ay, float adx, float ady, float ar,
        float bx, float by, float bdx, float bdy, float br) {
    float dcx = ax - bx, dcy = ay - by;
    float ra = 0.5f * sqrtf(adx * adx + ady * ady);
    float rb = 0.5f * sqrtf(bdx * bdx + bdy * bdy);
    float lim = ra + rb + 1e-3f;
    if (dcx * dcx + dcy * dcy > lim * lim) return 0.0f;

    float csa = cosf(ar), sna = sinf(ar);
    float csb = cosf(br), snb = sinf(br);
    float cax[4], cay[4], cbx[4], cby[4];
    const float SX[4] = {0.5f, 0.5f, -0.5f, -0.5f};
    const float SY[4] = {0.5f, -0.5f, -0.5f, 0.5f};
#pragma unroll
    for (int i = 0; i < 4; ++i) {
        float lx = SX[i] * adx, ly = SY[i] * ady;
        cax[i] = lx * csa - ly * sna + ax;
        cay[i] = lx * sna + ly * csa + ay;
        float mx = SX[i] * bdx, my = SY[i] * bdy;
        cbx[i] = mx * csb - my * snb + bx;
        cby[i] = mx * snb + my * csb + by;
    }
    float qx[24], qy[24];
    int m = 0;
#pragma unroll
    for (int i = 0; i < 4; ++i)
        if (pt_in_box(cax[i], cay[i], bx, by, bdx, bdy, csb, snb)) {
            qx[m] = cax[i]; qy[m] = cay[i]; ++m;
        }
#pragma unroll
    for (int i = 0; i < 4; ++i)
        if (pt_in_box(cbx[i], cby[i], ax, ay, adx, ady, csa, sna)) {
            qx[m] = cbx[i]; qy[m] = cby[i]; ++m;
        }
#pragma unroll
    for (int i = 0; i < 4; ++i) {
        float a0x = cax[i], a0y = cay[i];
        float d1x = cax[(i + 1) & 3] - a0x, d1y = cay[(i + 1) & 3] - a0y;
#pragma unroll
        for (int j = 0; j < 4; ++j) {
            float b0x = cbx[j], b0y = cby[j];
            float d2x = cbx[(j + 1) & 3] - b0x, d2y = cby[(j + 1) & 3] - b0y;
            float r0x = b0x - a0x, r0y = b0y - a0y;
            float den = d1x * d2y - d1y * d2x;
            bool nz = fabsf(den) > 1e-8f;
            float sden = nz ? den : 1.0f;
            float t = (r0x * d2y - r0y * d2x) / sden;
            float u = (r0x * d1y - r0y * d1x) / sden;
            if (nz && t >= 0.0f && t <= 1.0f && u >= 0.0f && u <= 1.0f) {
                qx[m] = a0x + t * d1x;
                qy[m] = a0y + t * d1y;
                ++m;
            }
        }
    }
    if (m < 3) return 0.0f;

    float sx = 0.0f, sy = 0.0f;
    for (int i = 0; i < m; ++i) { sx += qx[i]; sy += qy[i]; }
    float ctrx = sx / (float)m, ctry = sy / (float)m;
    float va[24];
    for (int i = 0; i < m; ++i) {
        float cx = qx[i] - ctrx, cy = qy[i] - ctry;
        qx[i] = cx; qy[i] = cy;
        va[i] = atan2f(cy, cx);
    }
    for (int i = 1; i < m; ++i) {
        float kx = qx[i], ky = qy[i], ka = va[i];
        int j = i - 1;
        while (j >= 0 && va[j] > ka) {
            qx[j + 1] = qx[j]; qy[j + 1] = qy[j]; va[j + 1] = va[j];
            --j;
        }
        qx[j + 1] = kx; qy[j + 1] = ky; va[j + 1] = ka;
    }
    float s = 0.0f;
    for (int i = 0; i < m; ++i) {
        int n2 = (i + 1 < m) ? i + 1 : 0;
        s += qx[i] * qy[n2] - qy[i] * qx[n2];
    }
    return 0.5f * fabsf(s);
}

// ---------------------------------------------------------------------------
// prep2: everything elementwise + argsort + inits. Block 1024.
// Bitonic with register pairs: j<64 steps via shfl_xor (no barrier),
// j>=64 via LDS (2 barriers each) -> 20 barriers instead of 55.
// ---------------------------------------------------------------------------
__global__ __launch_bounds__(1024) void prep2_kernel(
        const float* __restrict__ labels, const float* __restrict__ cls,
        const float* __restrict__ gt, const float* __restrict__ pred,
        float* __restrict__ out, int* __restrict__ order,
        float* __restrict__ sbox, float4* __restrict__ circ_s,
        float4* __restrict__ circ_g, float4* __restrict__ circ_p,
        u64* __restrict__ sup, u64* __restrict__ rowmax,
        unsigned int* __restrict__ cnt) {
    int tid = threadIdx.x;
    float lab = labels[tid];
    float sig = 1.0f / (1.0f + expf(-cls[tid]));
    out[tid] = (sig > 0.55f && lab > 0.55f) ? 1.0f : 0.0f;
    out[NB + tid] = lab;

#pragma unroll
    for (int t = 0; t < 16; ++t) sup[tid * 16 + t] = 0ULL;
    rowmax[tid] = 1023ULL;  // pack(iou=0.0f, j=0): (0<<32)|(1023-0)
    if (tid < 2) cnt[tid] = 0u;

    {
        float gx = gt[tid * 8 + 0], gy = gt[tid * 8 + 1];
        float gdx = gt[tid * 8 + 3], gdy = gt[tid * 8 + 4];
        circ_g[tid] = make_float4(gx, gy, 0.5f * sqrtf(gdx * gdx + gdy * gdy), 0.0f);
        float px = pred[tid * 7 + 0], py = pred[tid * 7 + 1];
        float pdx = pred[tid * 7 + 3], pdy = pred[tid * 7 + 4];
        circ_p[tid] = make_float4(px, py, 0.5f * sqrtf(pdx * pdx + pdy * pdy), 0.0f);
    }

    // bitonic argsort: descending key, ascending idx on ties.
    __shared__ float key_s[NB];
    __shared__ int idx_s[NB];
    float k = lab;
    int id = tid;
    for (int ksz = 2; ksz <= NB; ksz <<= 1) {
        for (int j = ksz >> 1; j > 0; j >>= 1) {
            bool dir_asc = (tid & ksz) == 0;
            float ok; int oi;
            if (j >= 64) {
                key_s[tid] = k; idx_s[tid] = id;
                __syncthreads();
                ok = key_s[tid ^ j]; oi = idx_s[tid ^ j];
                __syncthreads();
            } else {
                ok = __shfl_xor(k, j, 64);
                oi = __shfl_xor(id, j, 64);
            }
            bool isLow = (tid & j) == 0;
            bool pre = (k > ok) || (k == ok && id < oi);  // mine precedes other
            bool wantMine = (pre == (isLow == dir_asc));
            if (!wantMine) { k = ok; id = oi; }
        }
    }
    order[tid] = id;
    const float* g = &gt[id * 8];
#pragma unroll
    for (int c = 0; c < 7; ++c) sbox[tid * 8 + c] = g[c];
    sbox[tid * 8 + 7] = 0.0f;
    float sdx = g[3], sdy = g[4];
    circ_s[tid] = make_float4(g[0], g[1], 0.5f * sqrtf(sdx * sdx + sdy * sdy), 0.0f);
}

// ---------------------------------------------------------------------------
// cand_kernel: circle test for all pairs; ballot-compact into worklists.
// grid (4, 1024, 2), block 256. z=0: sorted gt pairs (j>i). z=1: pred x gt.
// ---------------------------------------------------------------------------
__global__ __launch_bounds__(256) void cand_kernel(
        const float4* __restrict__ circ_s, const float4* __restrict__ circ_p,
        const float4* __restrict__ circ_g, unsigned int* __restrict__ list,
        unsigned int* __restrict__ cnt) {
    int which = blockIdx.z;
    int i = blockIdx.y;
    int j = blockIdx.x * 256 + threadIdx.x;
    bool q = false;
    if (which == 0) {
        if (j > i) {
            float4 A = circ_s[i], B = circ_s[j];
            float dx = A.x - B.x, dy = A.y - B.y;
            float lim = A.z + B.z + 1e-3f;
            q = (dx * dx + dy * dy) <= lim * lim;
        }
    } else {
        float4 A = circ_p[i], B = circ_g[j];
        float dx = A.x - B.x, dy = A.y - B.y;
        float lim = A.z + B.z + 1e-3f;
        q = (dx * dx + dy * dy) <= lim * lim;
    }
    u64 m = __ballot(q ? 1 : 0);
    if (m == 0ULL) return;  // wave-uniform
    int lane = threadIdx.x & 63;
    int leader = __ffsll(m) - 1;
    unsigned int base = 0;
    if (lane == leader) base = atomicAdd(&cnt[which], (unsigned int)__popcll(m));
    base = (unsigned int)__shfl((int)base, leader, 64);
    if (q) {
        unsigned int pos = base + (unsigned int)__popcll(m & ((1ULL << lane) - 1ULL));
        if (pos < CAP) list[(unsigned)which * CAP + pos] = (unsigned int)((i << 10) | j);
    }
}

// ---------------------------------------------------------------------------
// evalA: full rotated IoU on gt-pair worklist -> suppression bits.
// ---------------------------------------------------------------------------
__global__ __launch_bounds__(256) void evalA_kernel(
        const float* __restrict__ sbox, const unsigned int* __restrict__ list,
        const unsigned int* __restrict__ cnt, u64* __restrict__ sup) {
    unsigned int n = min(cnt[0], CAP);
    for (unsigned int t = blockIdx.x * 256 + threadIdx.x; t < n;
         t += gridDim.x * 256) {
        unsigned int p = list[t];
        int i = p >> 10, j = p & 1023;
        const float* A = &sbox[i * 8];
        const float* B = &sbox[j * 8];
        float inter = rect_inter_area(A[0], A[1], A[3], A[4], A[6],
                                      B[0], B[1], B[3], B[4], B[6]);
        float iou = inter / fmaxf(A[3] * A[4] + B[3] * B[4] - inter, 1e-8f);
        if (iou > 0.1f)
            atomicOr(&sup[i * 16 + (j >> 6)], 1ULL << (j & 63));
    }
}

// ---------------------------------------------------------------------------
// nms_seq2: sequential greedy scan. Wave 0's 64 lanes redundantly hold the
// 16-word keep mask (static register indices via templates). Per visited box:
// broadcast LDS read of the row, AND only words >= W (lower words of row
// i >= W*64 are structurally zero). Critical chain: ffs -> ds_read -> and.
// ---------------------------------------------------------------------------
template <int P, int W>
__device__ __forceinline__ void scan_word(u64 (&kw)[16], const u64* sup_s) {
    u64 rem = kw[W];
    while (rem) {
        int b = __ffsll(rem) - 1;
        int row = (W * 64 + b) - P * 256;
        const u64* r = sup_s + row * 16;
        u64 rw = r[W];
        u64 tmp[16];
#pragma unroll
        for (int t = W + 1; t < 16; ++t) tmp[t] = r[t];
        kw[W] &= ~rw;
        rem = (b >= 63) ? 0ULL : (kw[W] & (~0ULL << (b + 1)));
#pragma unroll
        for (int t = W + 1; t < 16; ++t) kw[t] &= ~tmp[t];
    }
}

template <int P>
__device__ __forceinline__ void scan_phase(u64 (&kw)[16], const u64* sup_s) {
    scan_word<P, P * 4 + 0>(kw, sup_s);
    scan_word<P, P * 4 + 1>(kw, sup_s);
    scan_word<P, P * 4 + 2>(kw, sup_s);
    scan_word<P, P * 4 + 3>(kw, sup_s);
}

__global__ __launch_bounds__(1024) void nms_seq2_kernel(
        const u64* __restrict__ sup, const int* __restrict__ order,
        int* __restrict__ sampled) {
    __shared__ u64 sup_s[256 * 16];
    __shared__ u64 keep_s[16];
    int tid = threadIdx.x;
    u64 kw[16];
#pragma unroll
    for (int t = 0; t < 16; ++t) kw[t] = ~0ULL;

    for (int t = tid; t < 4096; t += 1024) sup_s[t] = sup[t];
    __syncthreads();
    if (tid < 64) scan_phase<0>(kw, sup_s);
    __syncthreads();
    for (int t = tid; t < 4096; t += 1024) sup_s[t] = sup[4096 + t];
    __syncthreads();
    if (tid < 64) scan_phase<1>(kw, sup_s);
    __syncthreads();
    for (int t = tid; t < 4096; t += 1024) sup_s[t] = sup[8192 + t];
    __syncthreads();
    if (tid < 64) scan_phase<2>(kw, sup_s);
    __syncthreads();
    for (int t = tid; t < 4096; t += 1024) sup_s[t] = sup[12288 + t];
    __syncthreads();
    if (tid < 64) scan_phase<3>(kw, sup_s);
    __syncthreads();

    if (tid < 16) keep_s[tid] = kw[0] , keep_s[tid] = kw[tid];
    __syncthreads();
    int bit = (int)((keep_s[tid >> 6] >> (tid & 63)) & 1ULL);
    sampled[order[tid]] = bit;
}

// ---------------------------------------------------------------------------
// evalB: full IoU3D on pred x gt worklist; packed (iou, first-idx) atomicMax.
// ---------------------------------------------------------------------------
__global__ __launch_bounds__(256) void evalB_kernel(
        const float* __restrict__ pred, const float* __restrict__ gt,
        const int* __restrict__ sampled, const unsigned int* __restrict__ list,
        const unsigned int* __restrict__ cnt, u64* __restrict__ rowmax) {
    unsigned int n = min(cnt[1], CAP);
    for (unsigned int t = blockIdx.x * 256 + threadIdx.x; t < n;
         t += gridDim.x * 256) {
        unsigned int p = list[CAP + t];
        int i = p >> 10, j = p & 1023;
        if (!sampled[j]) continue;
        float Ax = pred[i * 7 + 0], Ay = pred[i * 7 + 1], Az = pred[i * 7 + 2];
        float Adx = pred[i * 7 + 3], Ady = pred[i * 7 + 4], Adz = pred[i * 7 + 5];
        float Ar = pred[i * 7 + 6];
        float Bx = gt[j * 8 + 0], By = gt[j * 8 + 1], Bz = gt[j * 8 + 2];
        float Bdx = gt[j * 8 + 3], Bdy = gt[j * 8 + 4], Bdz = gt[j * 8 + 5];
        float Br = gt[j * 8 + 6];
        float inter = rect_inter_area(Ax, Ay, Adx, Ady, Ar,
                                      Bx, By, Bdx, Bdy, Br);
        float amax = Az + Adz * 0.5f, amin = Az - Adz * 0.5f;
        float bmax = Bz + Bdz * 0.5f, bmin = Bz - Bdz * 0.5f;
        float oh = fmaxf(fminf(amax, bmax) - fmaxf(amin, bmin), 0.0f);
        float inter3d = inter * oh;
        float va = Adx * Ady * Adz, vb = Bdx * Bdy * Bdz;
        float iou = inter3d / fmaxf(va + vb - inter3d, 1e-8f);
        u64 pk = (((u64)__float_as_uint(iou)) << 32) | (u64)(1023 - j);
        atomicMax(&rowmax[i], pk);
    }
}

__global__ __launch_bounds__(256) void fin_kernel(
        const u64* __restrict__ rowmax, float* __restrict__ out) {
    int i = blockIdx.x * 256 + threadIdx.x;
    u64 v = rowmax[i];
    float fv = __uint_as_float((unsigned int)(v >> 32));
    int j = 1023 - (int)(v & 0xFFFFFFFFULL);
    float mo = (fv > 0.75f) ? 1.0f : ((fv < 0.25f) ? 0.0f : fv);
    out[2 * NB + i] = mo;
    out[3 * NB + i] = (float)j;
}

// ---------------------------------------------------------------------------
// Fallback (round-1) dense kernels, used only if ws_size is too small.
// ---------------------------------------------------------------------------
__global__ __launch_bounds__(1024) void prep_kernel(
        const float* __restrict__ labels, const float* __restrict__ cls,
        const float* __restrict__ gt, float* __restrict__ out,
        int* __restrict__ order, float* __restrict__ sbox) {
    int tid = threadIdx.x;
    float lab = labels[tid];
    float sig = 1.0f / (1.0f + expf(-cls[tid]));
    out[tid] = (sig > 0.55f && lab > 0.55f) ? 1.0f : 0.0f;
    out[NB + tid] = lab;
    __shared__ float key[NB];
    __shared__ int idx[NB];
    key[tid] = lab;
    idx[tid] = tid;
    __syncthreads();
    for (int k = 2; k <= NB; k <<= 1) {
        for (int j = k >> 1; j > 0; j >>= 1) {
            int p = tid ^ j;
            if (p > tid) {
                float k1 = key[tid], k2 = key[p];
                int i1 = idx[tid], i2 = idx[p];
                bool lessPT = (k2 > k1) || (k2 == k1 && i2 < i1);
                bool asc = (tid & k) == 0;
                bool doswap = asc ? lessPT : !lessPT;
                if (doswap) {
                    key[tid] = k2; key[p] = k1;
                    idx[tid] = i2; idx[p] = i1;
                }
            }
            __syncthreads();
        }
    }
    int o = idx[tid];
    order[tid] = o;
#pragma unroll
    for (int c = 0; c < 7; ++c) sbox[tid * 8 + c] = gt[o * 8 + c];
    sbox[tid * 8 + 7] = 0.0f;
}

__global__ __launch_bounds__(256) void sup_kernel(
        const float* __restrict__ sbox, u64* __restrict__ sup) {
    int i = blockIdx.y;
    int j = blockIdx.x * 256 + threadIdx.x;
    int word = j >> 6;
    int lane = threadIdx.x & 63;
    int wmaxj = (word << 6) + 63;
    if (wmaxj <= i) {
        if (lane == 0) sup[i * 16 + word] = 0ULL;
        return;
    }
    bool pred = false;
    if (j > i) {
        const float* A = &sbox[i * 8];
        const float* B = &sbox[j * 8];
        float inter = rect_inter_area(A[0], A[1], A[3], A[4], A[6],
                                      B[0], B[1], B[3], B[4], B[6]);
        float iou = inter / fmaxf(A[3] * A[4] + B[3] * B[4] - inter, 1e-8f);
        pred = iou > 0.1f;
    }
    u64 m = __ballot(pred);
    if (lane == 0) sup[i * 16 + word] = m;
}

__global__ __launch_bounds__(1024) void iou3d_kernel(
        const float* __restrict__ pred, const float* __restrict__ gt,
        const int* __restrict__ sampled, float* __restrict__ out) {
    int i = blockIdx.x;
    int j = threadIdx.x;
    float Ax = pred[i * 7 + 0], Ay = pred[i * 7 + 1], Az = pred[i * 7 + 2];
    float Adx = pred[i * 7 + 3], Ady = pred[i * 7 + 4], Adz = pred[i * 7 + 5];
    float Ar = pred[i * 7 + 6];
    float msk = sampled[j] ? 1.0f : 0.0f;
    float Bx = gt[j * 8 + 0] * msk, By = gt[j * 8 + 1] * msk;
    float Bz = gt[j * 8 + 2] * msk;
    float Bdx = gt[j * 8 + 3] * msk, Bdy = gt[j * 8 + 4] * msk;
    float Bdz = gt[j * 8 + 5] * msk;
    float Br = gt[j * 8 + 6] * msk;
    float inter = rect_inter_area(Ax, Ay, Adx, Ady, Ar, Bx, By, Bdx, Bdy, Br);
    float amax = Az + Adz * 0.5f, amin = Az - Adz * 0.5f;
    float bmax = Bz + Bdz * 0.5f, bmin = Bz - Bdz * 0.5f;
    float oh = fmaxf(fminf(amax, bmax) - fmaxf(amin, bmin), 0.0f);
    float inter3d = inter * oh;
    float va = Adx * Ady * Adz, vb = Bdx * Bdy * Bdz;
    float iou = inter3d / fmaxf(va + vb - inter3d, 1e-8f);
    float bv = iou;
    int bi = j;
#pragma unroll
    for (int off = 32; off > 0; off >>= 1) {
        float ov = __shfl_down(bv, off, 64);
        int oi = __shfl_down(bi, off, 64);
        if (ov > bv || (ov == bv && oi < bi)) { bv = ov; bi = oi; }
    }
    __shared__ float wv[16];
    __shared__ int wi[16];
    int lane = threadIdx.x & 63, wid = threadIdx.x >> 6;
    if (lane == 0) { wv[wid] = bv; wi[wid] = bi; }
    __syncthreads();
    if (threadIdx.x == 0) {
        float fv = wv[0];
        int fi = wi[0];
#pragma unroll
        for (int t = 1; t < 16; ++t)
            if (wv[t] > fv || (wv[t] == fv && wi[t] < fi)) { fv = wv[t]; fi = wi[t]; }
        float mo = (fv > 0.75f) ? 1.0f : ((fv < 0.25f) ? 0.0f : fv);
        out[2 * NB + i] = mo;
        out[3 * NB + i] = (float)fi;
    }
}

// ---------------------------------------------------------------------------
// Workspace layout (fast path):
//   [0,       4096)    int   order[1024]
//   [4096,    36864)   float sbox[1024*8]
//   [36864,   40960)   int   sampled[1024]
//   [40960,   172032)  u64   sup[1024*16]
//   [172032,  188416)  float4 circ_s[1024]
//   [188416,  204800)  float4 circ_g[1024]
//   [204800,  221184)  float4 circ_p[1024]
//   [221184,  229376)  u64   rowmax[1024]
//   [229376,  229440)  uint  cnt[2] (+pad)
//   [229440,  229440+4*CAP)     uint listA
//   [229440+4*CAP, +8*CAP)      uint listB
// ---------------------------------------------------------------------------
extern "C" void kernel_launch(void* const* d_in, const int* in_sizes, int n_in,
                              void* d_out, int out_size, void* d_ws, size_t ws_size,
                              hipStream_t stream) {
    const float* labels = (const float*)d_in[0];
    const float* pred   = (const float*)d_in[1];
    const float* gt     = (const float*)d_in[2];
    const float* cls    = (const float*)d_in[3];
    float* out = (float*)d_out;

    char* ws = (char*)d_ws;
    int* order   = (int*)ws;
    float* sbox  = (float*)(ws + 4096);
    int* sampled = (int*)(ws + 36864);
    u64* sup     = (u64*)(ws + 40960);
    float4* circ_s = (float4*)(ws + 172032);
    float4* circ_g = (float4*)(ws + 188416);
    float4* circ_p = (float4*)(ws + 204800);
    u64* rowmax  = (u64*)(ws + 221184);
    unsigned int* cnt  = (unsigned int*)(ws + 229376);
    unsigned int* list = (unsigned int*)(ws + 229440);

    const size_t WS_NEEDED = 229440 + (size_t)8 * CAP;

    if (ws_size >= WS_NEEDED) {
        prep2_kernel<<<1, 1024, 0, stream>>>(labels, cls, gt, pred, out, order,
                                             sbox, circ_s, circ_g, circ_p, sup,
                                             rowmax, cnt);
        cand_kernel<<<dim3(4, 1024, 2), 256, 0, stream>>>(circ_s, circ_p,
                                                          circ_g, list, cnt);
        evalA_kernel<<<128, 256, 0, stream>>>(sbox, list, cnt, sup);
        nms_seq2_kernel<<<1, 1024, 0, stream>>>(sup, order, sampled);
        evalB_kernel<<<128, 256, 0, stream>>>(pred, gt, sampled, list, cnt,
                                              rowmax);
        fin_kernel<<<4, 256, 0, stream>>>(rowmax, out);
    } else {
        prep_kernel<<<1, 1024, 0, stream>>>(labels, cls, gt, out, order, sbox);
        sup_kernel<<<dim3(4, 1024), 256, 0, stream>>>(sbox, sup);
        nms_seq2_kernel<<<1, 1024, 0, stream>>>(sup, order, sampled);
        iou3d_kernel<<<1024, 1024, 0, stream>>>(pred, gt, sampled, out);
    }
}

// Round 3
// 229.162 us; speedup vs baseline: 1.4135x; 1.4135x over previous
//
#include <hip/hip_runtime.h>
#include <math.h>

// ---------------------------------------------------------------------------
// PreLossSampler (N=1024):
//   out = [reg_valid | labels | max_overlaps | gt_assignment]  (4096 float32)
//
// Pipeline (fast path):
//   prep2   : reg_valid, labels, bitonic argsort(-labels) (shfl for j<64),
//             gather sorted gt boxes, circumscribed circles, init sup/rowmax/cnt.
//   cand2(A): 128 persistent blocks grid-stride gt x gt pairs (sorted space,
//             j>i), circle-reject, BLOCK-LOCAL LDS compaction, one global
//             atomicAdd per flush (~1/block) -> listA.
//   evalA   : full rotated-IoU on dense listA -> suppression bits (atomicOr).
//   nms_seq2: sequential greedy NMS; wave-0 lanes redundantly hold the
//             1024-bit keep mask in 16 statically-indexed u64 registers;
//             per visited box one broadcast LDS row read + ANDs.
//   cand2(B): pred x gt pairs, filtered by sampled[j] AND circle test -> listB.
//   evalB   : full IoU3D on dense listB; packed (iou,first-idx) u64 atomicMax.
//   fin     : unpack rowmax -> out[2], out[3].
//
// Rejected pairs have polygon-intersection area exactly 0 in the reference
// (circle reject is value-preserving); non-sampled gt give iou 0 which never
// beats the rowmax init pack(0.0f, j=0).
// ---------------------------------------------------------------------------

#define NB 1024
#define CAP 131072u

typedef unsigned long long u64;

__device__ __forceinline__ bool pt_in_box(float px, float py,
        float bx, float by, float bdx, float bdy, float cs, float sn) {
    float dx = px - bx, dy = py - by;
    float lx = dx * cs + dy * sn;
    float ly = dy * cs - dx * sn;
    return (fabsf(lx) <= bdx * 0.5f + 1e-5f) && (fabsf(ly) <= bdy * 0.5f + 1e-5f);
}

// Rotated-rectangle intersection area; arithmetic identical to the validated
// round-1 kernel (absmax 0.0).
__device__ float rect_inter_area(
        float ax, float ay, float adx, float ady, float ar,
        float bx, float by, float bdx, float bdy, float br) {
    float dcx = ax - bx, dcy = ay - by;
    float ra = 0.5f * sqrtf(adx * adx + ady * ady);
    float rb = 0.5f * sqrtf(bdx * bdx + bdy * bdy);
    float lim = ra + rb + 1e-3f;
    if (dcx * dcx + dcy * dcy > lim * lim) return 0.0f;

    float csa = cosf(ar), sna = sinf(ar);
    float csb = cosf(br), snb = sinf(br);
    float cax[4], cay[4], cbx[4], cby[4];
    const float SX[4] = {0.5f, 0.5f, -0.5f, -0.5f};
    const float SY[4] = {0.5f, -0.5f, -0.5f, 0.5f};
#pragma unroll
    for (int i = 0; i < 4; ++i) {
        float lx = SX[i] * adx, ly = SY[i] * ady;
        cax[i] = lx * csa - ly * sna + ax;
        cay[i] = lx * sna + ly * csa + ay;
        float mx = SX[i] * bdx, my = SY[i] * bdy;
        cbx[i] = mx * csb - my * snb + bx;
        cby[i] = mx * snb + my * csb + by;
    }
    float qx[24], qy[24];
    int m = 0;
#pragma unroll
    for (int i = 0; i < 4; ++i)
        if (pt_in_box(cax[i], cay[i], bx, by, bdx, bdy, csb, snb)) {
            qx[m] = cax[i]; qy[m] = cay[i]; ++m;
        }
#pragma unroll
    for (int i = 0; i < 4; ++i)
        if (pt_in_box(cbx[i], cby[i], ax, ay, adx, ady, csa, sna)) {
            qx[m] = cbx[i]; qy[m] = cby[i]; ++m;
        }
#pragma unroll
    for (int i = 0; i < 4; ++i) {
        float a0x = cax[i], a0y = cay[i];
        float d1x = cax[(i + 1) & 3] - a0x, d1y = cay[(i + 1) & 3] - a0y;
#pragma unroll
        for (int j = 0; j < 4; ++j) {
            float b0x = cbx[j], b0y = cby[j];
            float d2x = cbx[(j + 1) & 3] - b0x, d2y = cby[(j + 1) & 3] - b0y;
            float r0x = b0x - a0x, r0y = b0y - a0y;
            float den = d1x * d2y - d1y * d2x;
            bool nz = fabsf(den) > 1e-8f;
            float sden = nz ? den : 1.0f;
            float t = (r0x * d2y - r0y * d2x) / sden;
            float u = (r0x * d1y - r0y * d1x) / sden;
            if (nz && t >= 0.0f && t <= 1.0f && u >= 0.0f && u <= 1.0f) {
                qx[m] = a0x + t * d1x;
                qy[m] = a0y + t * d1y;
                ++m;
            }
        }
    }
    if (m < 3) return 0.0f;

    float sx = 0.0f, sy = 0.0f;
    for (int i = 0; i < m; ++i) { sx += qx[i]; sy += qy[i]; }
    float ctrx = sx / (float)m, ctry = sy / (float)m;
    float va[24];
    for (int i = 0; i < m; ++i) {
        float cx = qx[i] - ctrx, cy = qy[i] - ctry;
        qx[i] = cx; qy[i] = cy;
        va[i] = atan2f(cy, cx);
    }
    for (int i = 1; i < m; ++i) {
        float kx = qx[i], ky = qy[i], ka = va[i];
        int j = i - 1;
        while (j >= 0 && va[j] > ka) {
            qx[j + 1] = qx[j]; qy[j + 1] = qy[j]; va[j + 1] = va[j];
            --j;
        }
        qx[j + 1] = kx; qy[j + 1] = ky; va[j + 1] = ka;
    }
    float s = 0.0f;
    for (int i = 0; i < m; ++i) {
        int n2 = (i + 1 < m) ? i + 1 : 0;
        s += qx[i] * qy[n2] - qy[i] * qx[n2];
    }
    return 0.5f * fabsf(s);
}

// ---------------------------------------------------------------------------
// prep2
// ---------------------------------------------------------------------------
__global__ __launch_bounds__(1024) void prep2_kernel(
        const float* __restrict__ labels, const float* __restrict__ cls,
        const float* __restrict__ gt, const float* __restrict__ pred,
        float* __restrict__ out, int* __restrict__ order,
        float* __restrict__ sbox, float4* __restrict__ circ_s,
        float4* __restrict__ circ_g, float4* __restrict__ circ_p,
        u64* __restrict__ sup, u64* __restrict__ rowmax,
        unsigned int* __restrict__ cnt) {
    int tid = threadIdx.x;
    float lab = labels[tid];
    float sig = 1.0f / (1.0f + expf(-cls[tid]));
    out[tid] = (sig > 0.55f && lab > 0.55f) ? 1.0f : 0.0f;
    out[NB + tid] = lab;

#pragma unroll
    for (int t = 0; t < 16; ++t) sup[tid * 16 + t] = 0ULL;
    rowmax[tid] = 1023ULL;  // pack(iou=0.0f, j=0)
    if (tid < 2) cnt[tid] = 0u;

    {
        float gx = gt[tid * 8 + 0], gy = gt[tid * 8 + 1];
        float gdx = gt[tid * 8 + 3], gdy = gt[tid * 8 + 4];
        circ_g[tid] = make_float4(gx, gy, 0.5f * sqrtf(gdx * gdx + gdy * gdy), 0.0f);
        float px = pred[tid * 7 + 0], py = pred[tid * 7 + 1];
        float pdx = pred[tid * 7 + 3], pdy = pred[tid * 7 + 4];
        circ_p[tid] = make_float4(px, py, 0.5f * sqrtf(pdx * pdx + pdy * pdy), 0.0f);
    }

    __shared__ float key_s[NB];
    __shared__ int idx_s[NB];
    float k = lab;
    int id = tid;
    for (int ksz = 2; ksz <= NB; ksz <<= 1) {
        for (int j = ksz >> 1; j > 0; j >>= 1) {
            bool dir_asc = (tid & ksz) == 0;
            float ok; int oi;
            if (j >= 64) {
                key_s[tid] = k; idx_s[tid] = id;
                __syncthreads();
                ok = key_s[tid ^ j]; oi = idx_s[tid ^ j];
                __syncthreads();
            } else {
                ok = __shfl_xor(k, j, 64);
                oi = __shfl_xor(id, j, 64);
            }
            bool isLow = (tid & j) == 0;
            bool pre = (k > ok) || (k == ok && id < oi);
            bool wantMine = (pre == (isLow == dir_asc));
            if (!wantMine) { k = ok; id = oi; }
        }
    }
    order[tid] = id;
    const float* g = &gt[id * 8];
#pragma unroll
    for (int c = 0; c < 7; ++c) sbox[tid * 8 + c] = g[c];
    sbox[tid * 8 + 7] = 0.0f;
    float sdx = g[3], sdy = g[4];
    circ_s[tid] = make_float4(g[0], g[1], 0.5f * sqrtf(sdx * sdx + sdy * sdy), 0.0f);
}

// ---------------------------------------------------------------------------
// cand2: persistent blocks, block-local LDS compaction, one global atomic
// per flush. mode 0: gt x gt (sorted space, j>i), ca=circ_s, cb=circ_s.
// mode 1: pred x gt, ca=circ_p, cb=circ_g, sampled filter.
// grid 128 x 256; 1M pair space -> exactly 32 rounds.
// ---------------------------------------------------------------------------
#define CBLK 128
#define CBUF 2048

__global__ __launch_bounds__(256) void cand2_kernel(
        const float4* __restrict__ ca, const float4* __restrict__ cb,
        const int* __restrict__ sampled, int mode,
        unsigned int* __restrict__ list, unsigned int* __restrict__ cnt) {
    __shared__ unsigned int buf[CBUF];
    __shared__ unsigned int bcnt;
    __shared__ unsigned int gbase;
    int tid = threadIdx.x;
    int lane = tid & 63;
    if (tid == 0) bcnt = 0u;
    __syncthreads();

    const unsigned int stride = CBLK * 256u;
    const unsigned int rounds = (1024u * 1024u) / stride;  // 32
    unsigned int t0 = blockIdx.x * 256u + tid;

    for (unsigned int r = 0; r < rounds; ++r) {
        unsigned int t = t0 + r * stride;
        int i = (int)(t >> 10), j = (int)(t & 1023u);
        bool q;
        if (mode == 0) {
            q = j > i;
        } else {
            q = sampled[j] != 0;
        }
        if (q) {
            float4 A = ca[i], B = cb[j];
            float dx = A.x - B.x, dy = A.y - B.y;
            float lim = A.z + B.z + 1e-3f;
            q = (dx * dx + dy * dy) <= lim * lim;
        }
        u64 m = __ballot(q ? 1 : 0);
        if (m) {
            int leader = __ffsll(m) - 1;
            unsigned int base = 0;
            if (lane == leader)
                base = atomicAdd(&bcnt, (unsigned int)__popcll(m));
            base = (unsigned int)__shfl((int)base, leader, 64);
            if (q) {
                unsigned int pos =
                    base + (unsigned int)__popcll(m & ((1ULL << lane) - 1ULL));
                if (pos < CBUF) buf[pos] = (unsigned int)((i << 10) | j);
            }
        }
        __syncthreads();
        if (bcnt >= CBUF - 256u) {  // flush before possible overflow
            if (tid == 0) gbase = atomicAdd(cnt, bcnt);
            __syncthreads();
            unsigned int n = min(bcnt, (unsigned int)CBUF);
            for (unsigned int s = tid; s < n; s += 256u) {
                unsigned int p = gbase + s;
                if (p < CAP) list[p] = buf[s];
            }
            __syncthreads();
            if (tid == 0) bcnt = 0u;
            __syncthreads();
        }
    }
    // final flush
    if (bcnt > 0u) {
        if (tid == 0) gbase = atomicAdd(cnt, bcnt);
        __syncthreads();
        unsigned int n = min(bcnt, (unsigned int)CBUF);
        for (unsigned int s = tid; s < n; s += 256u) {
            unsigned int p = gbase + s;
            if (p < CAP) list[p] = buf[s];
        }
    }
}

// ---------------------------------------------------------------------------
// evalA: full rotated IoU on dense gt-pair worklist -> suppression bits.
// ---------------------------------------------------------------------------
__global__ __launch_bounds__(256) void evalA_kernel(
        const float* __restrict__ sbox, const unsigned int* __restrict__ list,
        const unsigned int* __restrict__ cnt, u64* __restrict__ sup) {
    unsigned int n = min(cnt[0], CAP);
    for (unsigned int t = blockIdx.x * 256 + threadIdx.x; t < n;
         t += gridDim.x * 256) {
        unsigned int p = list[t];
        int i = p >> 10, j = p & 1023;
        const float* A = &sbox[i * 8];
        const float* B = &sbox[j * 8];
        float inter = rect_inter_area(A[0], A[1], A[3], A[4], A[6],
                                      B[0], B[1], B[3], B[4], B[6]);
        float iou = inter / fmaxf(A[3] * A[4] + B[3] * B[4] - inter, 1e-8f);
        if (iou > 0.1f)
            atomicOr(&sup[i * 16 + (j >> 6)], 1ULL << (j & 63));
    }
}

// ---------------------------------------------------------------------------
// nms_seq2
// ---------------------------------------------------------------------------
template <int P, int W>
__device__ __forceinline__ void scan_word(u64 (&kw)[16], const u64* sup_s) {
    u64 rem = kw[W];
    while (rem) {
        int b = __ffsll(rem) - 1;
        int row = (W * 64 + b) - P * 256;
        const u64* r = sup_s + row * 16;
        u64 rw = r[W];
        u64 tmp[16];
#pragma unroll
        for (int t = W + 1; t < 16; ++t) tmp[t] = r[t];
        kw[W] &= ~rw;
        rem = (b >= 63) ? 0ULL : (kw[W] & (~0ULL << (b + 1)));
#pragma unroll
        for (int t = W + 1; t < 16; ++t) kw[t] &= ~tmp[t];
    }
}

template <int P>
__device__ __forceinline__ void scan_phase(u64 (&kw)[16], const u64* sup_s) {
    scan_word<P, P * 4 + 0>(kw, sup_s);
    scan_word<P, P * 4 + 1>(kw, sup_s);
    scan_word<P, P * 4 + 2>(kw, sup_s);
    scan_word<P, P * 4 + 3>(kw, sup_s);
}

__global__ __launch_bounds__(1024) void nms_seq2_kernel(
        const u64* __restrict__ sup, const int* __restrict__ order,
        int* __restrict__ sampled) {
    __shared__ u64 sup_s[256 * 16];
    __shared__ u64 keep_s[16];
    int tid = threadIdx.x;
    u64 kw[16];
#pragma unroll
    for (int t = 0; t < 16; ++t) kw[t] = ~0ULL;

    for (int t = tid; t < 4096; t += 1024) sup_s[t] = sup[t];
    __syncthreads();
    if (tid < 64) scan_phase<0>(kw, sup_s);
    __syncthreads();
    for (int t = tid; t < 4096; t += 1024) sup_s[t] = sup[4096 + t];
    __syncthreads();
    if (tid < 64) scan_phase<1>(kw, sup_s);
    __syncthreads();
    for (int t = tid; t < 4096; t += 1024) sup_s[t] = sup[8192 + t];
    __syncthreads();
    if (tid < 64) scan_phase<2>(kw, sup_s);
    __syncthreads();
    for (int t = tid; t < 4096; t += 1024) sup_s[t] = sup[12288 + t];
    __syncthreads();
    if (tid < 64) scan_phase<3>(kw, sup_s);
    __syncthreads();

    // all 64 lanes of wave 0 hold identical kw; lane t<16 writes word t
    if (tid < 64) {
#pragma unroll
        for (int t = 0; t < 16; ++t)
            if (tid == t) keep_s[t] = kw[t];
    }
    __syncthreads();
    int bit = (int)((keep_s[tid >> 6] >> (tid & 63)) & 1ULL);
    sampled[order[tid]] = bit;
}

// ---------------------------------------------------------------------------
// evalB: full IoU3D on dense pred x sampled-gt worklist.
// ---------------------------------------------------------------------------
__global__ __launch_bounds__(256) void evalB_kernel(
        const float* __restrict__ pred, const float* __restrict__ gt,
        const unsigned int* __restrict__ list,
        const unsigned int* __restrict__ cnt, u64* __restrict__ rowmax) {
    unsigned int n = min(cnt[1], CAP);
    for (unsigned int t = blockIdx.x * 256 + threadIdx.x; t < n;
         t += gridDim.x * 256) {
        unsigned int p = list[CAP + t];
        int i = p >> 10, j = p & 1023;
        float Ax = pred[i * 7 + 0], Ay = pred[i * 7 + 1], Az = pred[i * 7 + 2];
        float Adx = pred[i * 7 + 3], Ady = pred[i * 7 + 4], Adz = pred[i * 7 + 5];
        float Ar = pred[i * 7 + 6];
        float Bx = gt[j * 8 + 0], By = gt[j * 8 + 1], Bz = gt[j * 8 + 2];
        float Bdx = gt[j * 8 + 3], Bdy = gt[j * 8 + 4], Bdz = gt[j * 8 + 5];
        float Br = gt[j * 8 + 6];
        float inter = rect_inter_area(Ax, Ay, Adx, Ady, Ar,
                                      Bx, By, Bdx, Bdy, Br);
        float amax = Az + Adz * 0.5f, amin = Az - Adz * 0.5f;
        float bmax = Bz + Bdz * 0.5f, bmin = Bz - Bdz * 0.5f;
        float oh = fmaxf(fminf(amax, bmax) - fmaxf(amin, bmin), 0.0f);
        float inter3d = inter * oh;
        float va = Adx * Ady * Adz, vb = Bdx * Bdy * Bdz;
        float iou = inter3d / fmaxf(va + vb - inter3d, 1e-8f);
        u64 pk = (((u64)__float_as_uint(iou)) << 32) | (u64)(1023 - j);
        atomicMax(&rowmax[i], pk);
    }
}

__global__ __launch_bounds__(256) void fin_kernel(
        const u64* __restrict__ rowmax, float* __restrict__ out) {
    int i = blockIdx.x * 256 + threadIdx.x;
    u64 v = rowmax[i];
    float fv = __uint_as_float((unsigned int)(v >> 32));
    int j = 1023 - (int)(v & 0xFFFFFFFFULL);
    float mo = (fv > 0.75f) ? 1.0f : ((fv < 0.25f) ? 0.0f : fv);
    out[2 * NB + i] = mo;
    out[3 * NB + i] = (float)j;
}

// ---------------------------------------------------------------------------
// Fallback dense kernels (only if ws too small).
// ---------------------------------------------------------------------------
__global__ __launch_bounds__(1024) void prep_kernel(
        const float* __restrict__ labels, const float* __restrict__ cls,
        const float* __restrict__ gt, float* __restrict__ out,
        int* __restrict__ order, float* __restrict__ sbox) {
    int tid = threadIdx.x;
    float lab = labels[tid];
    float sig = 1.0f / (1.0f + expf(-cls[tid]));
    out[tid] = (sig > 0.55f && lab > 0.55f) ? 1.0f : 0.0f;
    out[NB + tid] = lab;
    __shared__ float key[NB];
    __shared__ int idx[NB];
    key[tid] = lab;
    idx[tid] = tid;
    __syncthreads();
    for (int k = 2; k <= NB; k <<= 1) {
        for (int j = k >> 1; j > 0; j >>= 1) {
            int p = tid ^ j;
            if (p > tid) {
                float k1 = key[tid], k2 = key[p];
                int i1 = idx[tid], i2 = idx[p];
                bool lessPT = (k2 > k1) || (k2 == k1 && i2 < i1);
                bool asc = (tid & k) == 0;
                bool doswap = asc ? lessPT : !lessPT;
                if (doswap) {
                    key[tid] = k2; key[p] = k1;
                    idx[tid] = i2; idx[p] = i1;
                }
            }
            __syncthreads();
        }
    }
    int o = idx[tid];
    order[tid] = o;
#pragma unroll
    for (int c = 0; c < 7; ++c) sbox[tid * 8 + c] = gt[o * 8 + c];
    sbox[tid * 8 + 7] = 0.0f;
}

__global__ __launch_bounds__(256) void sup_kernel(
        const float* __restrict__ sbox, u64* __restrict__ sup) {
    int i = blockIdx.y;
    int j = blockIdx.x * 256 + threadIdx.x;
    int word = j >> 6;
    int lane = threadIdx.x & 63;
    int wmaxj = (word << 6) + 63;
    if (wmaxj <= i) {
        if (lane == 0) sup[i * 16 + word] = 0ULL;
        return;
    }
    bool pred = false;
    if (j > i) {
        const float* A = &sbox[i * 8];
        const float* B = &sbox[j * 8];
        float inter = rect_inter_area(A[0], A[1], A[3], A[4], A[6],
                                      B[0], B[1], B[3], B[4], B[6]);
        float iou = inter / fmaxf(A[3] * A[4] + B[3] * B[4] - inter, 1e-8f);
        pred = iou > 0.1f;
    }
    u64 m = __ballot(pred);
    if (lane == 0) sup[i * 16 + word] = m;
}

__global__ __launch_bounds__(1024) void iou3d_kernel(
        const float* __restrict__ pred, const float* __restrict__ gt,
        const int* __restrict__ sampled, float* __restrict__ out) {
    int i = blockIdx.x;
    int j = threadIdx.x;
    float Ax = pred[i * 7 + 0], Ay = pred[i * 7 + 1], Az = pred[i * 7 + 2];
    float Adx = pred[i * 7 + 3], Ady = pred[i * 7 + 4], Adz = pred[i * 7 + 5];
    float Ar = pred[i * 7 + 6];
    float msk = sampled[j] ? 1.0f : 0.0f;
    float Bx = gt[j * 8 + 0] * msk, By = gt[j * 8 + 1] * msk;
    float Bz = gt[j * 8 + 2] * msk;
    float Bdx = gt[j * 8 + 3] * msk, Bdy = gt[j * 8 + 4] * msk;
    float Bdz = gt[j * 8 + 5] * msk;
    float Br = gt[j * 8 + 6] * msk;
    float inter = rect_inter_area(Ax, Ay, Adx, Ady, Ar, Bx, By, Bdx, Bdy, Br);
    float amax = Az + Adz * 0.5f, amin = Az - Adz * 0.5f;
    float bmax = Bz + Bdz * 0.5f, bmin = Bz - Bdz * 0.5f;
    float oh = fmaxf(fminf(amax, bmax) - fmaxf(amin, bmin), 0.0f);
    float inter3d = inter * oh;
    float va = Adx * Ady * Adz, vb = Bdx * Bdy * Bdz;
    float iou = inter3d / fmaxf(va + vb - inter3d, 1e-8f);
    float bv = iou;
    int bi = j;
#pragma unroll
    for (int off = 32; off > 0; off >>= 1) {
        float ov = __shfl_down(bv, off, 64);
        int oi = __shfl_down(bi, off, 64);
        if (ov > bv || (ov == bv && oi < bi)) { bv = ov; bi = oi; }
    }
    __shared__ float wv[16];
    __shared__ int wi[16];
    int lane = threadIdx.x & 63, wid = threadIdx.x >> 6;
    if (lane == 0) { wv[wid] = bv; wi[wid] = bi; }
    __syncthreads();
    if (threadIdx.x == 0) {
        float fv = wv[0];
        int fi = wi[0];
#pragma unroll
        for (int t = 1; t < 16; ++t)
            if (wv[t] > fv || (wv[t] == fv && wi[t] < fi)) { fv = wv[t]; fi = wi[t]; }
        float mo = (fv > 0.75f) ? 1.0f : ((fv < 0.25f) ? 0.0f : fv);
        out[2 * NB + i] = mo;
        out[3 * NB + i] = (float)fi;
    }
}

// ---------------------------------------------------------------------------
// Workspace layout:
//   [0,       4096)    int   order[1024]
//   [4096,    36864)   float sbox[1024*8]
//   [36864,   40960)   int   sampled[1024]
//   [40960,   172032)  u64   sup[1024*16]
//   [172032,  188416)  float4 circ_s[1024]
//   [188416,  204800)  float4 circ_g[1024]
//   [204800,  221184)  float4 circ_p[1024]
//   [221184,  229376)  u64   rowmax[1024]
//   [229376,  229440)  uint  cnt[2] (+pad)
//   [229440, +4*CAP)   uint  listA
//   [+4*CAP, +8*CAP)   uint  listB
// ---------------------------------------------------------------------------
extern "C" void kernel_launch(void* const* d_in, const int* in_sizes, int n_in,
                              void* d_out, int out_size, void* d_ws, size_t ws_size,
                              hipStream_t stream) {
    const float* labels = (const float*)d_in[0];
    const float* pred   = (const float*)d_in[1];
    const float* gt     = (const float*)d_in[2];
    const float* cls    = (const float*)d_in[3];
    float* out = (float*)d_out;

    char* ws = (char*)d_ws;
    int* order   = (int*)ws;
    float* sbox  = (float*)(ws + 4096);
    int* sampled = (int*)(ws + 36864);
    u64* sup     = (u64*)(ws + 40960);
    float4* circ_s = (float4*)(ws + 172032);
    float4* circ_g = (float4*)(ws + 188416);
    float4* circ_p = (float4*)(ws + 204800);
    u64* rowmax  = (u64*)(ws + 221184);
    unsigned int* cnt  = (unsigned int*)(ws + 229376);
    unsigned int* list = (unsigned int*)(ws + 229440);

    const size_t WS_NEEDED = 229440 + (size_t)8 * CAP;

    if (ws_size >= WS_NEEDED) {
        prep2_kernel<<<1, 1024, 0, stream>>>(labels, cls, gt, pred, out, order,
                                             sbox, circ_s, circ_g, circ_p, sup,
                                             rowmax, cnt);
        cand2_kernel<<<CBLK, 256, 0, stream>>>(circ_s, circ_s, sampled, 0,
                                               list, &cnt[0]);
        evalA_kernel<<<64, 256, 0, stream>>>(sbox, list, cnt, sup);
        nms_seq2_kernel<<<1, 1024, 0, stream>>>(sup, order, sampled);
        cand2_kernel<<<CBLK, 256, 0, stream>>>(circ_p, circ_g, sampled, 1,
                                               list + CAP, &cnt[1]);
        evalB_kernel<<<64, 256, 0, stream>>>(pred, gt, list, cnt, rowmax);
        fin_kernel<<<4, 256, 0, stream>>>(rowmax, out);
    } else {
        prep_kernel<<<1, 1024, 0, stream>>>(labels, cls, gt, out, order, sbox);
        sup_kernel<<<dim3(4, 1024), 256, 0, stream>>>(sbox, sup);
        nms_seq2_kernel<<<1, 1024, 0, stream>>>(sup, order, sampled);
        iou3d_kernel<<<1024, 1024, 0, stream>>>(pred, gt, sampled, out);
    }
}

// Round 4
// 203.420 us; speedup vs baseline: 1.5924x; 1.1265x over previous
//
#include <hip/hip_runtime.h>
#include <math.h>

// ---------------------------------------------------------------------------
// PreLossSampler (N=1024):
//   out = [reg_valid | labels | max_overlaps | gt_assignment]  (4096 float32)
//
// Pipeline:
//   prep2    : reg_valid, labels, bitonic argsort(-labels), gather sorted gt,
//              circles, init sup/rowmax/cnt.
//   cand2(A) : gt x gt (sorted, j>i) circle-reject -> listA (LDS compaction).
//   evalA    : exact rotated-IoU on listA -> suppression bits (atomicOr).
//              Polygon clip is fully register-resident (sorting NETWORK, no
//              dynamic indexing -> no scratch).
//   nms_seq3 : greedy NMS, single wave; rows staged in REGISTERS (lane b
//              holds row W*64+b), intra-word scan via ffs+shfl broadcast,
//              cross-word suppression via one OR-reduction per word.
//   cand2(B) : pred x gt, sampled[j]-filtered circle test -> listB.
//   evalB    : exact IoU3D on listB; packed (iou, first-idx) u64 atomicMax.
//   fin      : unpack rowmax -> out[2], out[3].
//
// Exactness: circle-rejected pairs have polygon area exactly 0 in the
// reference; the network sort reproduces stable argsort via (angle, slot)
// lexicographic keys; masked +0.0f adds are exact. Validated absmax 0.0.
// ---------------------------------------------------------------------------

#define NB 1024
#define CAP 131072u

typedef unsigned long long u64;

__device__ __forceinline__ bool pt_in_box(float px, float py,
        float bx, float by, float bdx, float bdy, float cs, float sn) {
    float dx = px - bx, dy = py - by;
    float lx = dx * cs + dy * sn;
    float ly = dy * cs - dx * sn;
    return (fabsf(lx) <= bdx * 0.5f + 1e-5f) && (fabsf(ly) <= bdy * 0.5f + 1e-5f);
}

// Monotone sortable key: (total-ordered float bits, slot) packed in u64.
// +0.0f add canonicalizes -0 so -0/+0 compare equal -> slot tiebreak (stable).
__device__ __forceinline__ u64 fkey(float f, int slot) {
    unsigned u = __float_as_uint(f + 0.0f);
    u = (u & 0x80000000u) ? ~u : (u | 0x80000000u);
    return ((u64)u << 5) | (unsigned)slot;
}

// Rotated-rectangle intersection area. Candidate construction order, centroid
// sum order, stable angle sort, and shoelace order replicate the reference
// exactly (same arithmetic as the validated round-1 kernel); the stable sort
// is realized as a 32-slot bitonic network on (angle,slot) keys so all array
// indexing is static (registers, no scratch).
__device__ float rect_inter_area(
        float ax, float ay, float adx, float ady, float ar,
        float bx, float by, float bdx, float bdy, float br) {
    float dcx = ax - bx, dcy = ay - by;
    float ra = 0.5f * sqrtf(adx * adx + ady * ady);
    float rb = 0.5f * sqrtf(bdx * bdx + bdy * bdy);
    float lim = ra + rb + 1e-3f;
    if (dcx * dcx + dcy * dcy > lim * lim) return 0.0f;

    float csa = cosf(ar), sna = sinf(ar);
    float csb = cosf(br), snb = sinf(br);
    float cax[4], cay[4], cbx[4], cby[4];
    const float SX[4] = {0.5f, 0.5f, -0.5f, -0.5f};
    const float SY[4] = {0.5f, -0.5f, -0.5f, 0.5f};
#pragma unroll
    for (int i = 0; i < 4; ++i) {
        float lx = SX[i] * adx, ly = SY[i] * ady;
        cax[i] = lx * csa - ly * sna + ax;
        cay[i] = lx * sna + ly * csa + ay;
        float mx = SX[i] * bdx, my = SY[i] * bdy;
        cbx[i] = mx * csb - my * snb + bx;
        cby[i] = mx * snb + my * csb + by;
    }

    // 24 fixed candidate slots in reference order + validity bitmask.
    float qx[24], qy[24];
    unsigned vmask = 0u;
#pragma unroll
    for (int i = 0; i < 4; ++i) {
        qx[i] = cax[i]; qy[i] = cay[i];
        if (pt_in_box(cax[i], cay[i], bx, by, bdx, bdy, csb, snb))
            vmask |= 1u << i;
        qx[4 + i] = cbx[i]; qy[4 + i] = cby[i];
        if (pt_in_box(cbx[i], cby[i], ax, ay, adx, ady, csa, sna))
            vmask |= 1u << (4 + i);
    }
#pragma unroll
    for (int i = 0; i < 4; ++i) {
        float a0x = cax[i], a0y = cay[i];
        float d1x = cax[(i + 1) & 3] - a0x, d1y = cay[(i + 1) & 3] - a0y;
#pragma unroll
        for (int j = 0; j < 4; ++j) {
            int s = 8 + i * 4 + j;
            float b0x = cbx[j], b0y = cby[j];
            float d2x = cbx[(j + 1) & 3] - b0x, d2y = cby[(j + 1) & 3] - b0y;
            float r0x = b0x - a0x, r0y = b0y - a0y;
            float den = d1x * d2y - d1y * d2x;
            bool nz = fabsf(den) > 1e-8f;
            float sden = nz ? den : 1.0f;
            float t = (r0x * d2y - r0y * d2x) / sden;
            float u = (r0x * d1y - r0y * d1x) / sden;
            qx[s] = a0x + t * d1x;
            qy[s] = a0y + t * d1y;
            if (nz && t >= 0.0f && t <= 1.0f && u >= 0.0f && u <= 1.0f)
                vmask |= 1u << s;
        }
    }
    int kc = __popc(vmask);
    if (kc < 3) return 0.0f;

    float sx = 0.0f, sy = 0.0f;
#pragma unroll
    for (int s = 0; s < 24; ++s) {
        bool v = (vmask >> s) & 1u;
        sx += v ? qx[s] : 0.0f;
        sy += v ? qy[s] : 0.0f;
    }
    float ctrx = sx / (float)kc, ctry = sy / (float)kc;

    float px[32], py[32];
    u64 kk[32];
#pragma unroll
    for (int s = 0; s < 24; ++s) {
        bool v = (vmask >> s) & 1u;
        float cx = v ? qx[s] - ctrx : 0.0f;
        float cy = v ? qy[s] - ctry : 0.0f;
        float an = v ? atan2f(cy, cx) : 1e9f;
        px[s] = cx; py[s] = cy;
        kk[s] = fkey(an, s);
    }
#pragma unroll
    for (int s = 24; s < 32; ++s) {
        px[s] = 0.0f; py[s] = 0.0f;
        kk[s] = fkey(1e30f, s);
    }

    // 32-element bitonic sorting network, ascending by key (all-static idx).
#pragma unroll
    for (int kk2 = 2; kk2 <= 32; kk2 <<= 1) {
#pragma unroll
        for (int jj = kk2 >> 1; jj > 0; jj >>= 1) {
#pragma unroll
            for (int ii = 0; ii < 32; ++ii) {
                int ll = ii ^ jj;
                if (ll > ii) {
                    bool up = (ii & kk2) == 0;
                    bool sw = up ? (kk[ii] > kk[ll]) : (kk[ii] < kk[ll]);
                    if (sw) {
                        u64 tk = kk[ii]; kk[ii] = kk[ll]; kk[ll] = tk;
                        float tx = px[ii]; px[ii] = px[ll]; px[ll] = tx;
                        float ty = py[ii]; py[ii] = py[ll]; py[ll] = ty;
                    }
                }
            }
        }
    }

    // Shoelace: terms 0..kc-2 in order, wrap term last (trailing +0 adds are
    // exact, so order matches the reference sum).
    float s = 0.0f;
#pragma unroll
    for (int i = 0; i < 23; ++i) {
        float cr = px[i] * py[i + 1] - py[i] * px[i + 1];
        s += (i + 1 < kc) ? cr : 0.0f;
    }
    float lx = 0.0f, ly = 0.0f;
#pragma unroll
    for (int i = 0; i < 24; ++i) {
        bool e = (i == kc - 1);
        lx = e ? px[i] : lx;
        ly = e ? py[i] : ly;
    }
    s += lx * py[0] - ly * px[0];
    return 0.5f * fabsf(s);
}

// ---------------------------------------------------------------------------
// prep2
// ---------------------------------------------------------------------------
__global__ __launch_bounds__(1024) void prep2_kernel(
        const float* __restrict__ labels, const float* __restrict__ cls,
        const float* __restrict__ gt, const float* __restrict__ pred,
        float* __restrict__ out, int* __restrict__ order,
        float* __restrict__ sbox, float4* __restrict__ circ_s,
        float4* __restrict__ circ_g, float4* __restrict__ circ_p,
        u64* __restrict__ sup, u64* __restrict__ rowmax,
        unsigned int* __restrict__ cnt) {
    int tid = threadIdx.x;
    float lab = labels[tid];
    float sig = 1.0f / (1.0f + expf(-cls[tid]));
    out[tid] = (sig > 0.55f && lab > 0.55f) ? 1.0f : 0.0f;
    out[NB + tid] = lab;

#pragma unroll
    for (int t = 0; t < 16; ++t) sup[tid * 16 + t] = 0ULL;
    rowmax[tid] = 1023ULL;  // pack(iou=0.0f, j=0)
    if (tid < 2) cnt[tid] = 0u;

    {
        float gx = gt[tid * 8 + 0], gy = gt[tid * 8 + 1];
        float gdx = gt[tid * 8 + 3], gdy = gt[tid * 8 + 4];
        circ_g[tid] = make_float4(gx, gy, 0.5f * sqrtf(gdx * gdx + gdy * gdy), 0.0f);
        float px = pred[tid * 7 + 0], py = pred[tid * 7 + 1];
        float pdx = pred[tid * 7 + 3], pdy = pred[tid * 7 + 4];
        circ_p[tid] = make_float4(px, py, 0.5f * sqrtf(pdx * pdx + pdy * pdy), 0.0f);
    }

    __shared__ float key_s[NB];
    __shared__ int idx_s[NB];
    float k = lab;
    int id = tid;
    for (int ksz = 2; ksz <= NB; ksz <<= 1) {
        for (int j = ksz >> 1; j > 0; j >>= 1) {
            bool dir_asc = (tid & ksz) == 0;
            float ok; int oi;
            if (j >= 64) {
                key_s[tid] = k; idx_s[tid] = id;
                __syncthreads();
                ok = key_s[tid ^ j]; oi = idx_s[tid ^ j];
                __syncthreads();
            } else {
                ok = __shfl_xor(k, j, 64);
                oi = __shfl_xor(id, j, 64);
            }
            bool isLow = (tid & j) == 0;
            bool pre = (k > ok) || (k == ok && id < oi);
            bool wantMine = (pre == (isLow == dir_asc));
            if (!wantMine) { k = ok; id = oi; }
        }
    }
    order[tid] = id;
    const float* g = &gt[id * 8];
#pragma unroll
    for (int c = 0; c < 7; ++c) sbox[tid * 8 + c] = g[c];
    sbox[tid * 8 + 7] = 0.0f;
    float sdx = g[3], sdy = g[4];
    circ_s[tid] = make_float4(g[0], g[1], 0.5f * sqrtf(sdx * sdx + sdy * sdy), 0.0f);
}

// ---------------------------------------------------------------------------
// cand2: persistent blocks, LDS compaction, ~1 global atomic per flush.
// mode 0: gt x gt (sorted, j>i). mode 1: pred x gt with sampled[j] filter.
// ---------------------------------------------------------------------------
#define CBLK 128
#define CBUF 2048

__global__ __launch_bounds__(256) void cand2_kernel(
        const float4* __restrict__ ca, const float4* __restrict__ cb,
        const int* __restrict__ sampled, int mode,
        unsigned int* __restrict__ list, unsigned int* __restrict__ cnt) {
    __shared__ unsigned int buf[CBUF];
    __shared__ unsigned int bcnt;
    __shared__ unsigned int gbase;
    int tid = threadIdx.x;
    int lane = tid & 63;
    if (tid == 0) bcnt = 0u;
    __syncthreads();

    const unsigned int stride = CBLK * 256u;
    const unsigned int rounds = (1024u * 1024u) / stride;  // 32
    unsigned int t0 = blockIdx.x * 256u + tid;

    for (unsigned int r = 0; r < rounds; ++r) {
        unsigned int t = t0 + r * stride;
        int i = (int)(t >> 10), j = (int)(t & 1023u);
        bool q;
        if (mode == 0) {
            q = j > i;
        } else {
            q = sampled[j] != 0;
        }
        if (q) {
            float4 A = ca[i], B = cb[j];
            float dx = A.x - B.x, dy = A.y - B.y;
            float lim = A.z + B.z + 1e-3f;
            q = (dx * dx + dy * dy) <= lim * lim;
        }
        u64 m = __ballot(q ? 1 : 0);
        if (m) {
            int leader = __ffsll(m) - 1;
            unsigned int base = 0;
            if (lane == leader)
                base = atomicAdd(&bcnt, (unsigned int)__popcll(m));
            base = (unsigned int)__shfl((int)base, leader, 64);
            if (q) {
                unsigned int pos =
                    base + (unsigned int)__popcll(m & ((1ULL << lane) - 1ULL));
                if (pos < CBUF) buf[pos] = (unsigned int)((i << 10) | j);
            }
        }
        __syncthreads();
        if (bcnt >= CBUF - 256u) {
            if (tid == 0) gbase = atomicAdd(cnt, bcnt);
            __syncthreads();
            unsigned int n = min(bcnt, (unsigned int)CBUF);
            for (unsigned int s = tid; s < n; s += 256u) {
                unsigned int p = gbase + s;
                if (p < CAP) list[p] = buf[s];
            }
            __syncthreads();
            if (tid == 0) bcnt = 0u;
            __syncthreads();
        }
    }
    if (bcnt > 0u) {
        if (tid == 0) gbase = atomicAdd(cnt, bcnt);
        __syncthreads();
        unsigned int n = min(bcnt, (unsigned int)CBUF);
        for (unsigned int s = tid; s < n; s += 256u) {
            unsigned int p = gbase + s;
            if (p < CAP) list[p] = buf[s];
        }
    }
}

// ---------------------------------------------------------------------------
// evalA: exact rotated IoU on listA -> suppression bits. 1-wave blocks so
// the register-resident clip (~200 VGPR) never spills.
// ---------------------------------------------------------------------------
__global__ __launch_bounds__(64, 1) void evalA_kernel(
        const float* __restrict__ sbox, const unsigned int* __restrict__ list,
        const unsigned int* __restrict__ cnt, u64* __restrict__ sup) {
    unsigned int n = min(cnt[0], CAP);
    for (unsigned int t = blockIdx.x * 64 + threadIdx.x; t < n;
         t += gridDim.x * 64) {
        unsigned int p = list[t];
        int i = p >> 10, j = p & 1023;
        const float* A = &sbox[i * 8];
        const float* B = &sbox[j * 8];
        float inter = rect_inter_area(A[0], A[1], A[3], A[4], A[6],
                                      B[0], B[1], B[3], B[4], B[6]);
        float iou = inter / fmaxf(A[3] * A[4] + B[3] * B[4] - inter, 1e-8f);
        if (iou > 0.1f)
            atomicOr(&sup[i * 16 + (j >> 6)], 1ULL << (j & 63));
    }
}

// ---------------------------------------------------------------------------
// nms_seq3: greedy NMS, one wave. Lane b stages row (W*64+b) in registers.
// Intra-word scan: wave-uniform ffs -> shfl broadcast of the row's own word.
// Cross-word: one 64-lane OR-reduction per remaining word, once per W.
// ---------------------------------------------------------------------------
__global__ __launch_bounds__(64) void nms_seq3_kernel(
        const u64* __restrict__ sup, const int* __restrict__ order,
        int* __restrict__ sampled) {
    int lane = threadIdx.x;
    u64 kw[16];
#pragma unroll
    for (int t = 0; t < 16; ++t) kw[t] = ~0ULL;

#pragma unroll
    for (int W = 0; W < 16; ++W) {
        // rows in block W have zero words below W (suppression is j>i only)
        u64 row[16];
#pragma unroll
        for (int t = 0; t < 16; ++t)
            row[t] = (t >= W) ? sup[(size_t)(W * 64 + lane) * 16 + t] : 0ULL;

        u64 rem = kw[W];  // wave-uniform
        while (rem) {
            int b = __ffsll(rem) - 1;                 // uniform
            u64 r = __shfl(row[W], b, 64);            // broadcast lane b
            kw[W] &= ~r;                              // bits in r are all > b
            rem = (b >= 63) ? 0ULL : (kw[W] & (~0ULL << (b + 1)));
        }
        u64 kept = kw[W];
        bool me = (kept >> lane) & 1ULL;
#pragma unroll
        for (int t = W + 1; t < 16; ++t) {
            u64 v = me ? row[t] : 0ULL;
#pragma unroll
            for (int off = 32; off > 0; off >>= 1)
                v |= __shfl_xor(v, off, 64);
            kw[t] &= ~v;
        }
    }

#pragma unroll
    for (int t = 0; t < 16; ++t) {
        int idx = t * 64 + lane;
        int bit = (int)((kw[t] >> lane) & 1ULL);
        sampled[order[idx]] = bit;
    }
}

// ---------------------------------------------------------------------------
// evalB: exact IoU3D on listB; packed (iou, first-idx) u64 atomicMax.
// ---------------------------------------------------------------------------
__global__ __launch_bounds__(64, 1) void evalB_kernel(
        const float* __restrict__ pred, const float* __restrict__ gt,
        const unsigned int* __restrict__ list,
        const unsigned int* __restrict__ cnt, u64* __restrict__ rowmax) {
    unsigned int n = min(cnt[1], CAP);
    for (unsigned int t = blockIdx.x * 64 + threadIdx.x; t < n;
         t += gridDim.x * 64) {
        unsigned int p = list[CAP + t];
        int i = p >> 10, j = p & 1023;
        float Ax = pred[i * 7 + 0], Ay = pred[i * 7 + 1], Az = pred[i * 7 + 2];
        float Adx = pred[i * 7 + 3], Ady = pred[i * 7 + 4], Adz = pred[i * 7 + 5];
        float Ar = pred[i * 7 + 6];
        float Bx = gt[j * 8 + 0], By = gt[j * 8 + 1], Bz = gt[j * 8 + 2];
        float Bdx = gt[j * 8 + 3], Bdy = gt[j * 8 + 4], Bdz = gt[j * 8 + 5];
        float Br = gt[j * 8 + 6];
        float inter = rect_inter_area(Ax, Ay, Adx, Ady, Ar,
                                      Bx, By, Bdx, Bdy, Br);
        float amax = Az + Adz * 0.5f, amin = Az - Adz * 0.5f;
        float bmax = Bz + Bdz * 0.5f, bmin = Bz - Bdz * 0.5f;
        float oh = fmaxf(fminf(amax, bmax) - fmaxf(amin, bmin), 0.0f);
        float inter3d = inter * oh;
        float va = Adx * Ady * Adz, vb = Bdx * Bdy * Bdz;
        float iou = inter3d / fmaxf(va + vb - inter3d, 1e-8f);
        u64 pk = (((u64)__float_as_uint(iou)) << 32) | (u64)(1023 - j);
        atomicMax(&rowmax[i], pk);
    }
}

__global__ __launch_bounds__(256) void fin_kernel(
        const u64* __restrict__ rowmax, float* __restrict__ out) {
    int i = blockIdx.x * 256 + threadIdx.x;
    u64 v = rowmax[i];
    float fv = __uint_as_float((unsigned int)(v >> 32));
    int j = 1023 - (int)(v & 0xFFFFFFFFULL);
    float mo = (fv > 0.75f) ? 1.0f : ((fv < 0.25f) ? 0.0f : fv);
    out[2 * NB + i] = mo;
    out[3 * NB + i] = (float)j;
}

// ---------------------------------------------------------------------------
// Fallback dense kernels (only if ws too small; may spill — unused in
// practice).
// ---------------------------------------------------------------------------
__global__ __launch_bounds__(1024) void prep_kernel(
        const float* __restrict__ labels, const float* __restrict__ cls,
        const float* __restrict__ gt, float* __restrict__ out,
        int* __restrict__ order, float* __restrict__ sbox) {
    int tid = threadIdx.x;
    float lab = labels[tid];
    float sig = 1.0f / (1.0f + expf(-cls[tid]));
    out[tid] = (sig > 0.55f && lab > 0.55f) ? 1.0f : 0.0f;
    out[NB + tid] = lab;
    __shared__ float key[NB];
    __shared__ int idx[NB];
    key[tid] = lab;
    idx[tid] = tid;
    __syncthreads();
    for (int k = 2; k <= NB; k <<= 1) {
        for (int j = k >> 1; j > 0; j >>= 1) {
            int p = tid ^ j;
            if (p > tid) {
                float k1 = key[tid], k2 = key[p];
                int i1 = idx[tid], i2 = idx[p];
                bool lessPT = (k2 > k1) || (k2 == k1 && i2 < i1);
                bool asc = (tid & k) == 0;
                bool doswap = asc ? lessPT : !lessPT;
                if (doswap) {
                    key[tid] = k2; key[p] = k1;
                    idx[tid] = i2; idx[p] = i1;
                }
            }
            __syncthreads();
        }
    }
    int o = idx[tid];
    order[tid] = o;
#pragma unroll
    for (int c = 0; c < 7; ++c) sbox[tid * 8 + c] = gt[o * 8 + c];
    sbox[tid * 8 + 7] = 0.0f;
}

__global__ __launch_bounds__(256) void sup_kernel(
        const float* __restrict__ sbox, u64* __restrict__ sup) {
    int i = blockIdx.y;
    int j = blockIdx.x * 256 + threadIdx.x;
    int word = j >> 6;
    int lane = threadIdx.x & 63;
    int wmaxj = (word << 6) + 63;
    if (wmaxj <= i) {
        if (lane == 0) sup[i * 16 + word] = 0ULL;
        return;
    }
    bool pred = false;
    if (j > i) {
        const float* A = &sbox[i * 8];
        const float* B = &sbox[j * 8];
        float inter = rect_inter_area(A[0], A[1], A[3], A[4], A[6],
                                      B[0], B[1], B[3], B[4], B[6]);
        float iou = inter / fmaxf(A[3] * A[4] + B[3] * B[4] - inter, 1e-8f);
        pred = iou > 0.1f;
    }
    u64 m = __ballot(pred);
    if (lane == 0) sup[i * 16 + word] = m;
}

__global__ __launch_bounds__(256) void iou3d_row_kernel(
        const float* __restrict__ pred, const float* __restrict__ gt,
        const int* __restrict__ sampled, u64* __restrict__ rowmax) {
    int i = blockIdx.y;
    int j = blockIdx.x * 256 + threadIdx.x;
    float Ax = pred[i * 7 + 0], Ay = pred[i * 7 + 1], Az = pred[i * 7 + 2];
    float Adx = pred[i * 7 + 3], Ady = pred[i * 7 + 4], Adz = pred[i * 7 + 5];
    float Ar = pred[i * 7 + 6];
    float msk = sampled[j] ? 1.0f : 0.0f;
    float Bx = gt[j * 8 + 0] * msk, By = gt[j * 8 + 1] * msk;
    float Bz = gt[j * 8 + 2] * msk;
    float Bdx = gt[j * 8 + 3] * msk, Bdy = gt[j * 8 + 4] * msk;
    float Bdz = gt[j * 8 + 5] * msk;
    float Br = gt[j * 8 + 6] * msk;
    float inter = rect_inter_area(Ax, Ay, Adx, Ady, Ar, Bx, By, Bdx, Bdy, Br);
    float amax = Az + Adz * 0.5f, amin = Az - Adz * 0.5f;
    float bmax = Bz + Bdz * 0.5f, bmin = Bz - Bdz * 0.5f;
    float oh = fmaxf(fminf(amax, bmax) - fmaxf(amin, bmin), 0.0f);
    float inter3d = inter * oh;
    float va = Adx * Ady * Adz, vb = Bdx * Bdy * Bdz;
    float iou = inter3d / fmaxf(va + vb - inter3d, 1e-8f);
    u64 pk = (((u64)__float_as_uint(iou)) << 32) | (u64)(1023 - j);
    atomicMax(&rowmax[i], pk);
}

// ---------------------------------------------------------------------------
// Workspace layout:
//   [0,       4096)    int   order[1024]
//   [4096,    36864)   float sbox[1024*8]
//   [36864,   40960)   int   sampled[1024]
//   [40960,   172032)  u64   sup[1024*16]
//   [172032,  188416)  float4 circ_s[1024]
//   [188416,  204800)  float4 circ_g[1024]
//   [204800,  221184)  float4 circ_p[1024]
//   [221184,  229376)  u64   rowmax[1024]
//   [229376,  229440)  uint  cnt[2] (+pad)
//   [229440, +4*CAP)   uint  listA
//   [+4*CAP, +8*CAP)   uint  listB
// ---------------------------------------------------------------------------
extern "C" void kernel_launch(void* const* d_in, const int* in_sizes, int n_in,
                              void* d_out, int out_size, void* d_ws, size_t ws_size,
                              hipStream_t stream) {
    const float* labels = (const float*)d_in[0];
    const float* pred   = (const float*)d_in[1];
    const float* gt     = (const float*)d_in[2];
    const float* cls    = (const float*)d_in[3];
    float* out = (float*)d_out;

    char* ws = (char*)d_ws;
    int* order   = (int*)ws;
    float* sbox  = (float*)(ws + 4096);
    int* sampled = (int*)(ws + 36864);
    u64* sup     = (u64*)(ws + 40960);
    float4* circ_s = (float4*)(ws + 172032);
    float4* circ_g = (float4*)(ws + 188416);
    float4* circ_p = (float4*)(ws + 204800);
    u64* rowmax  = (u64*)(ws + 221184);
    unsigned int* cnt  = (unsigned int*)(ws + 229376);
    unsigned int* list = (unsigned int*)(ws + 229440);

    const size_t WS_NEEDED = 229440 + (size_t)8 * CAP;

    if (ws_size >= WS_NEEDED) {
        prep2_kernel<<<1, 1024, 0, stream>>>(labels, cls, gt, pred, out, order,
                                             sbox, circ_s, circ_g, circ_p, sup,
                                             rowmax, cnt);
        cand2_kernel<<<CBLK, 256, 0, stream>>>(circ_s, circ_s, sampled, 0,
                                               list, &cnt[0]);
        evalA_kernel<<<256, 64, 0, stream>>>(sbox, list, cnt, sup);
        nms_seq3_kernel<<<1, 64, 0, stream>>>(sup, order, sampled);
        cand2_kernel<<<CBLK, 256, 0, stream>>>(circ_p, circ_g, sampled, 1,
                                               list + CAP, &cnt[1]);
        evalB_kernel<<<256, 64, 0, stream>>>(pred, gt, list, cnt, rowmax);
        fin_kernel<<<4, 256, 0, stream>>>(rowmax, out);
    } else {
        prep_kernel<<<1, 1024, 0, stream>>>(labels, cls, gt, out, order, sbox);
        sup_kernel<<<dim3(4, 1024), 256, 0, stream>>>(sbox, sup);
        nms_seq3_kernel<<<1, 64, 0, stream>>>(sup, order, sampled);
        iou3d_row_kernel<<<dim3(4, 1024), 256, 0, stream>>>(pred, gt, sampled,
                                                            rowmax);
        fin_kernel<<<4, 256, 0, stream>>>(rowmax, out);
    }
}

// Round 5
// 174.297 us; speedup vs baseline: 1.8585x; 1.1671x over previous
//
#include <hip/hip_runtime.h>
#include <math.h>

// ---------------------------------------------------------------------------
// PreLossSampler (N=1024):
//   out = [reg_valid | labels | max_overlaps | gt_assignment]  (4096 float32)
//
// Pipeline:
//   prep2    : reg_valid, labels, bitonic argsort(-labels), gather sorted gt,
//              circles, init sup/rowmax/cnt.
//   cand3(A) : gt x gt (sorted, j>i) circle-reject -> listA. One wave/block,
//              wave-private LDS buffer (2048 = worst-case pairs/block, so no
//              mid-loop flush), ballot-counted in registers, ZERO barriers,
//              one global atomicAdd per block.
//   evalA    : exact rotated-IoU on listA -> suppression bits (atomicOr).
//              Clip is fully register-resident (bitonic network, static idx).
//   nms_seq4 : greedy NMS, one wave. Per 64-box word: ONE 64-lane OR
//              butterfly (lane-local acc of kept rows), LDS broadcast of the
//              64 row-words, then a 64-step pure-VALU cndmask chain for the
//              intra-word greedy (no shfl in the dependent chain).
//   cand3(B) : pred x gt, sampled[j]-filtered circle test -> listB.
//   evalB    : exact IoU3D on listB; packed (iou, first-idx) u64 atomicMax.
//   fin      : unpack rowmax -> out[2], out[3].
//
// Exactness: circle-rejected pairs have polygon area exactly 0 in the
// reference; network sort reproduces stable argsort via (angle,slot) keys;
// masked +0.0f adds are exact. Validated absmax 0.0 (rounds 1-4).
// ---------------------------------------------------------------------------

#define NB 1024
#define CAP 131072u

typedef unsigned long long u64;

__device__ __forceinline__ bool pt_in_box(float px, float py,
        float bx, float by, float bdx, float bdy, float cs, float sn) {
    float dx = px - bx, dy = py - by;
    float lx = dx * cs + dy * sn;
    float ly = dy * cs - dx * sn;
    return (fabsf(lx) <= bdx * 0.5f + 1e-5f) && (fabsf(ly) <= bdy * 0.5f + 1e-5f);
}

// Monotone sortable key: (total-ordered float bits, slot) packed in u64.
__device__ __forceinline__ u64 fkey(float f, int slot) {
    unsigned u = __float_as_uint(f + 0.0f);
    u = (u & 0x80000000u) ? ~u : (u | 0x80000000u);
    return ((u64)u << 5) | (unsigned)slot;
}

// Rotated-rectangle intersection area; reference-exact ordering; all-static
// indexing (registers, no scratch).
__device__ float rect_inter_area(
        float ax, float ay, float adx, float ady, float ar,
        float bx, float by, float bdx, float bdy, float br) {
    float dcx = ax - bx, dcy = ay - by;
    float ra = 0.5f * sqrtf(adx * adx + ady * ady);
    float rb = 0.5f * sqrtf(bdx * bdx + bdy * bdy);
    float lim = ra + rb + 1e-3f;
    if (dcx * dcx + dcy * dcy > lim * lim) return 0.0f;

    float csa = cosf(ar), sna = sinf(ar);
    float csb = cosf(br), snb = sinf(br);
    float cax[4], cay[4], cbx[4], cby[4];
    const float SX[4] = {0.5f, 0.5f, -0.5f, -0.5f};
    const float SY[4] = {0.5f, -0.5f, -0.5f, 0.5f};
#pragma unroll
    for (int i = 0; i < 4; ++i) {
        float lx = SX[i] * adx, ly = SY[i] * ady;
        cax[i] = lx * csa - ly * sna + ax;
        cay[i] = lx * sna + ly * csa + ay;
        float mx = SX[i] * bdx, my = SY[i] * bdy;
        cbx[i] = mx * csb - my * snb + bx;
        cby[i] = mx * snb + my * csb + by;
    }

    float qx[24], qy[24];
    unsigned vmask = 0u;
#pragma unroll
    for (int i = 0; i < 4; ++i) {
        qx[i] = cax[i]; qy[i] = cay[i];
        if (pt_in_box(cax[i], cay[i], bx, by, bdx, bdy, csb, snb))
            vmask |= 1u << i;
        qx[4 + i] = cbx[i]; qy[4 + i] = cby[i];
        if (pt_in_box(cbx[i], cby[i], ax, ay, adx, ady, csa, sna))
            vmask |= 1u << (4 + i);
    }
#pragma unroll
    for (int i = 0; i < 4; ++i) {
        float a0x = cax[i], a0y = cay[i];
        float d1x = cax[(i + 1) & 3] - a0x, d1y = cay[(i + 1) & 3] - a0y;
#pragma unroll
        for (int j = 0; j < 4; ++j) {
            int s = 8 + i * 4 + j;
            float b0x = cbx[j], b0y = cby[j];
            float d2x = cbx[(j + 1) & 3] - b0x, d2y = cby[(j + 1) & 3] - b0y;
            float r0x = b0x - a0x, r0y = b0y - a0y;
            float den = d1x * d2y - d1y * d2x;
            bool nz = fabsf(den) > 1e-8f;
            float sden = nz ? den : 1.0f;
            float t = (r0x * d2y - r0y * d2x) / sden;
            float u = (r0x * d1y - r0y * d1x) / sden;
            qx[s] = a0x + t * d1x;
            qy[s] = a0y + t * d1y;
            if (nz && t >= 0.0f && t <= 1.0f && u >= 0.0f && u <= 1.0f)
                vmask |= 1u << s;
        }
    }
    int kc = __popc(vmask);
    if (kc < 3) return 0.0f;

    float sx = 0.0f, sy = 0.0f;
#pragma unroll
    for (int s = 0; s < 24; ++s) {
        bool v = (vmask >> s) & 1u;
        sx += v ? qx[s] : 0.0f;
        sy += v ? qy[s] : 0.0f;
    }
    float ctrx = sx / (float)kc, ctry = sy / (float)kc;

    float px[32], py[32];
    u64 kk[32];
#pragma unroll
    for (int s = 0; s < 24; ++s) {
        bool v = (vmask >> s) & 1u;
        float cx = v ? qx[s] - ctrx : 0.0f;
        float cy = v ? qy[s] - ctry : 0.0f;
        float an = v ? atan2f(cy, cx) : 1e9f;
        px[s] = cx; py[s] = cy;
        kk[s] = fkey(an, s);
    }
#pragma unroll
    for (int s = 24; s < 32; ++s) {
        px[s] = 0.0f; py[s] = 0.0f;
        kk[s] = fkey(1e30f, s);
    }

#pragma unroll
    for (int kk2 = 2; kk2 <= 32; kk2 <<= 1) {
#pragma unroll
        for (int jj = kk2 >> 1; jj > 0; jj >>= 1) {
#pragma unroll
            for (int ii = 0; ii < 32; ++ii) {
                int ll = ii ^ jj;
                if (ll > ii) {
                    bool up = (ii & kk2) == 0;
                    bool sw = up ? (kk[ii] > kk[ll]) : (kk[ii] < kk[ll]);
                    if (sw) {
                        u64 tk = kk[ii]; kk[ii] = kk[ll]; kk[ll] = tk;
                        float tx = px[ii]; px[ii] = px[ll]; px[ll] = tx;
                        float ty = py[ii]; py[ii] = py[ll]; py[ll] = ty;
                    }
                }
            }
        }
    }

    float s = 0.0f;
#pragma unroll
    for (int i = 0; i < 23; ++i) {
        float cr = px[i] * py[i + 1] - py[i] * px[i + 1];
        s += (i + 1 < kc) ? cr : 0.0f;
    }
    float lx = 0.0f, ly = 0.0f;
#pragma unroll
    for (int i = 0; i < 24; ++i) {
        bool e = (i == kc - 1);
        lx = e ? px[i] : lx;
        ly = e ? py[i] : ly;
    }
    s += lx * py[0] - ly * px[0];
    return 0.5f * fabsf(s);
}

// ---------------------------------------------------------------------------
// prep2
// ---------------------------------------------------------------------------
__global__ __launch_bounds__(1024) void prep2_kernel(
        const float* __restrict__ labels, const float* __restrict__ cls,
        const float* __restrict__ gt, const float* __restrict__ pred,
        float* __restrict__ out, int* __restrict__ order,
        float* __restrict__ sbox, float4* __restrict__ circ_s,
        float4* __restrict__ circ_g, float4* __restrict__ circ_p,
        u64* __restrict__ sup, u64* __restrict__ rowmax,
        unsigned int* __restrict__ cnt) {
    int tid = threadIdx.x;
    float lab = labels[tid];
    float sig = 1.0f / (1.0f + expf(-cls[tid]));
    out[tid] = (sig > 0.55f && lab > 0.55f) ? 1.0f : 0.0f;
    out[NB + tid] = lab;

#pragma unroll
    for (int t = 0; t < 16; ++t) sup[tid * 16 + t] = 0ULL;
    rowmax[tid] = 1023ULL;  // pack(iou=0.0f, j=0)
    if (tid < 2) cnt[tid] = 0u;

    {
        float gx = gt[tid * 8 + 0], gy = gt[tid * 8 + 1];
        float gdx = gt[tid * 8 + 3], gdy = gt[tid * 8 + 4];
        circ_g[tid] = make_float4(gx, gy, 0.5f * sqrtf(gdx * gdx + gdy * gdy), 0.0f);
        float px = pred[tid * 7 + 0], py = pred[tid * 7 + 1];
        float pdx = pred[tid * 7 + 3], pdy = pred[tid * 7 + 4];
        circ_p[tid] = make_float4(px, py, 0.5f * sqrtf(pdx * pdx + pdy * pdy), 0.0f);
    }

    __shared__ float key_s[NB];
    __shared__ int idx_s[NB];
    float k = lab;
    int id = tid;
    for (int ksz = 2; ksz <= NB; ksz <<= 1) {
        for (int j = ksz >> 1; j > 0; j >>= 1) {
            bool dir_asc = (tid & ksz) == 0;
            float ok; int oi;
            if (j >= 64) {
                key_s[tid] = k; idx_s[tid] = id;
                __syncthreads();
                ok = key_s[tid ^ j]; oi = idx_s[tid ^ j];
                __syncthreads();
            } else {
                ok = __shfl_xor(k, j, 64);
                oi = __shfl_xor(id, j, 64);
            }
            bool isLow = (tid & j) == 0;
            bool pre = (k > ok) || (k == ok && id < oi);
            bool wantMine = (pre == (isLow == dir_asc));
            if (!wantMine) { k = ok; id = oi; }
        }
    }
    order[tid] = id;
    const float* g = &gt[id * 8];
#pragma unroll
    for (int c = 0; c < 7; ++c) sbox[tid * 8 + c] = g[c];
    sbox[tid * 8 + 7] = 0.0f;
    float sdx = g[3], sdy = g[4];
    circ_s[tid] = make_float4(g[0], g[1], 0.5f * sqrtf(sdx * sdx + sdy * sdy), 0.0f);
}

// ---------------------------------------------------------------------------
// cand3: one wave per block, wave-private LDS buffer (2048 entries = worst
// case pairs scanned per block -> never overflows), register count via
// ballot, no barriers in the loop, one global atomicAdd per block.
// mode 0: gt x gt (sorted, j>i). mode 1: pred x gt with sampled[j] filter.
// ---------------------------------------------------------------------------
#define CB3 512

__global__ __launch_bounds__(64) void cand3_kernel(
        const float4* __restrict__ ca, const float4* __restrict__ cb,
        const int* __restrict__ sampled, int mode,
        unsigned int* __restrict__ list, unsigned int* __restrict__ cnt) {
    __shared__ unsigned int buf[2048];
    int lane = threadIdx.x;
    unsigned int nloc = 0;  // wave-uniform
    const unsigned int stride = CB3 * 64u;  // 32768
    unsigned int t = blockIdx.x * 64u + lane;
#pragma unroll
    for (unsigned int r = 0; r < 32; ++r, t += stride) {
        int i = (int)(t >> 10), j = (int)(t & 1023u);
        bool q = (mode == 0) ? (j > i) : (sampled[j] != 0);
        if (q) {
            float4 A = ca[i], B = cb[j];
            float dx = A.x - B.x, dy = A.y - B.y;
            float lim = A.z + B.z + 1e-3f;
            q = (dx * dx + dy * dy) <= lim * lim;
        }
        u64 m = __ballot(q ? 1 : 0);
        if (q) {
            unsigned int pos =
                nloc + (unsigned int)__popcll(m & ((1ULL << lane) - 1ULL));
            buf[pos] = (unsigned int)((i << 10) | j);
        }
        nloc += (unsigned int)__popcll(m);
    }
    __syncthreads();  // single wave: cheap; orders LDS writes vs reads below
    unsigned int base = 0;
    if (lane == 0 && nloc) base = atomicAdd(cnt, nloc);
    base = (unsigned int)__shfl((int)base, 0, 64);
    for (unsigned int s = lane; s < nloc; s += 64u) {
        unsigned int p = base + s;
        if (p < CAP) list[p] = buf[s];
    }
}

// ---------------------------------------------------------------------------
// evalA: exact rotated IoU on listA -> suppression bits. 1-wave blocks.
// ---------------------------------------------------------------------------
__global__ __launch_bounds__(64, 1) void evalA_kernel(
        const float* __restrict__ sbox, const unsigned int* __restrict__ list,
        const unsigned int* __restrict__ cnt, u64* __restrict__ sup) {
    unsigned int n = min(cnt[0], CAP);
    for (unsigned int t = blockIdx.x * 64 + threadIdx.x; t < n;
         t += gridDim.x * 64) {
        unsigned int p = list[t];
        int i = p >> 10, j = p & 1023;
        const float* A = &sbox[i * 8];
        const float* B = &sbox[j * 8];
        float inter = rect_inter_area(A[0], A[1], A[3], A[4], A[6],
                                      B[0], B[1], B[3], B[4], B[6]);
        float iou = inter / fmaxf(A[3] * A[4] + B[3] * B[4] - inter, 1e-8f);
        if (iou > 0.1f)
            atomicOr(&sup[i * 16 + (j >> 6)], 1ULL << (j & 63));
    }
}

// ---------------------------------------------------------------------------
// nms_seq4: greedy NMS, one wave. Lane b holds row (W*64+b).
//   per word W:
//     1. one 64-lane OR butterfly of lane-local acc[W] -> suppression from
//        kept boxes in words < W; kwW = ~that.
//     2. LDS-broadcast the 64 row-words (independent same-address reads),
//        then 64-step pure-VALU cndmask chain: kwW &= bit_b(kwW)?~r_b:~0.
//        (row bits are j>i only, so r_b never clears bits <= b.)
//     3. lanes whose box is kept OR their row into acc[t>W] (local, no shfl).
// ---------------------------------------------------------------------------
__global__ __launch_bounds__(64, 1) void nms_seq4_kernel(
        const u64* __restrict__ sup, const int* __restrict__ order,
        int* __restrict__ sampled) {
    __shared__ u64 bc[64];
    int lane = threadIdx.x;
    u64 kw[16];
    u64 acc[16];
#pragma unroll
    for (int t = 0; t < 16; ++t) acc[t] = 0ULL;

#pragma unroll
    for (int W = 0; W < 16; ++W) {
        // load this word-block's rows (words >= W; lower words are zero)
        u64 row[16];
#pragma unroll
        for (int t = 0; t < 16; ++t)
            row[t] = (t >= W) ? sup[(size_t)(W * 64 + lane) * 16 + t] : 0ULL;

        // 1. cross-word suppression for word W (one butterfly)
        u64 v = acc[W];
#pragma unroll
        for (int off = 32; off > 0; off >>= 1) v |= __shfl_xor(v, off, 64);
        u64 kwW = ~v;

        // 2. intra-word greedy via LDS broadcast + VALU chain
        bc[lane] = row[W];
        __syncthreads();
        u64 rb[64];
#pragma unroll
        for (int b = 0; b < 64; ++b) rb[b] = bc[b];
#pragma unroll
        for (int b = 0; b < 64; ++b) {
            bool kb = (kwW >> b) & 1ULL;
            kwW &= kb ? ~rb[b] : ~0ULL;
        }
        __syncthreads();

        kw[W] = kwW;

        // 3. kept lanes accumulate their row into future words (local only)
        bool me = (kwW >> lane) & 1ULL;
#pragma unroll
        for (int t = W + 1; t < 16; ++t) acc[t] |= me ? row[t] : 0ULL;
    }

#pragma unroll
    for (int t = 0; t < 16; ++t) {
        int idx = t * 64 + lane;
        int bit = (int)((kw[t] >> lane) & 1ULL);
        sampled[order[idx]] = bit;
    }
}

// ---------------------------------------------------------------------------
// evalB: exact IoU3D on listB; packed (iou, first-idx) u64 atomicMax.
// ---------------------------------------------------------------------------
__global__ __launch_bounds__(64, 1) void evalB_kernel(
        const float* __restrict__ pred, const float* __restrict__ gt,
        const unsigned int* __restrict__ list,
        const unsigned int* __restrict__ cnt, u64* __restrict__ rowmax) {
    unsigned int n = min(cnt[1], CAP);
    for (unsigned int t = blockIdx.x * 64 + threadIdx.x; t < n;
         t += gridDim.x * 64) {
        unsigned int p = list[CAP + t];
        int i = p >> 10, j = p & 1023;
        float Ax = pred[i * 7 + 0], Ay = pred[i * 7 + 1], Az = pred[i * 7 + 2];
        float Adx = pred[i * 7 + 3], Ady = pred[i * 7 + 4], Adz = pred[i * 7 + 5];
        float Ar = pred[i * 7 + 6];
        float Bx = gt[j * 8 + 0], By = gt[j * 8 + 1], Bz = gt[j * 8 + 2];
        float Bdx = gt[j * 8 + 3], Bdy = gt[j * 8 + 4], Bdz = gt[j * 8 + 5];
        float Br = gt[j * 8 + 6];
        float inter = rect_inter_area(Ax, Ay, Adx, Ady, Ar,
                                      Bx, By, Bdx, Bdy, Br);
        float amax = Az + Adz * 0.5f, amin = Az - Adz * 0.5f;
        float bmax = Bz + Bdz * 0.5f, bmin = Bz - Bdz * 0.5f;
        float oh = fmaxf(fminf(amax, bmax) - fmaxf(amin, bmin), 0.0f);
        float inter3d = inter * oh;
        float va = Adx * Ady * Adz, vb = Bdx * Bdy * Bdz;
        float iou = inter3d / fmaxf(va + vb - inter3d, 1e-8f);
        u64 pk = (((u64)__float_as_uint(iou)) << 32) | (u64)(1023 - j);
        atomicMax(&rowmax[i], pk);
    }
}

__global__ __launch_bounds__(256) void fin_kernel(
        const u64* __restrict__ rowmax, float* __restrict__ out) {
    int i = blockIdx.x * 256 + threadIdx.x;
    u64 v = rowmax[i];
    float fv = __uint_as_float((unsigned int)(v >> 32));
    int j = 1023 - (int)(v & 0xFFFFFFFFULL);
    float mo = (fv > 0.75f) ? 1.0f : ((fv < 0.25f) ? 0.0f : fv);
    out[2 * NB + i] = mo;
    out[3 * NB + i] = (float)j;
}

// ---------------------------------------------------------------------------
// Fallback dense kernels (only if ws too small).
// ---------------------------------------------------------------------------
__global__ __launch_bounds__(1024) void prep_kernel(
        const float* __restrict__ labels, const float* __restrict__ cls,
        const float* __restrict__ gt, float* __restrict__ out,
        int* __restrict__ order, float* __restrict__ sbox) {
    int tid = threadIdx.x;
    float lab = labels[tid];
    float sig = 1.0f / (1.0f + expf(-cls[tid]));
    out[tid] = (sig > 0.55f && lab > 0.55f) ? 1.0f : 0.0f;
    out[NB + tid] = lab;
    __shared__ float key[NB];
    __shared__ int idx[NB];
    key[tid] = lab;
    idx[tid] = tid;
    __syncthreads();
    for (int k = 2; k <= NB; k <<= 1) {
        for (int j = k >> 1; j > 0; j >>= 1) {
            int p = tid ^ j;
            if (p > tid) {
                float k1 = key[tid], k2 = key[p];
                int i1 = idx[tid], i2 = idx[p];
                bool lessPT = (k2 > k1) || (k2 == k1 && i2 < i1);
                bool asc = (tid & k) == 0;
                bool doswap = asc ? lessPT : !lessPT;
                if (doswap) {
                    key[tid] = k2; key[p] = k1;
                    idx[tid] = i2; idx[p] = i1;
                }
            }
            __syncthreads();
        }
    }
    int o = idx[tid];
    order[tid] = o;
#pragma unroll
    for (int c = 0; c < 7; ++c) sbox[tid * 8 + c] = gt[o * 8 + c];
    sbox[tid * 8 + 7] = 0.0f;
}

__global__ __launch_bounds__(256) void sup_kernel(
        const float* __restrict__ sbox, u64* __restrict__ sup) {
    int i = blockIdx.y;
    int j = blockIdx.x * 256 + threadIdx.x;
    int word = j >> 6;
    int lane = threadIdx.x & 63;
    int wmaxj = (word << 6) + 63;
    if (wmaxj <= i) {
        if (lane == 0) sup[i * 16 + word] = 0ULL;
        return;
    }
    bool pred = false;
    if (j > i) {
        const float* A = &sbox[i * 8];
        const float* B = &sbox[j * 8];
        float inter = rect_inter_area(A[0], A[1], A[3], A[4], A[6],
                                      B[0], B[1], B[3], B[4], B[6]);
        float iou = inter / fmaxf(A[3] * A[4] + B[3] * B[4] - inter, 1e-8f);
        pred = iou > 0.1f;
    }
    u64 m = __ballot(pred);
    if (lane == 0) sup[i * 16 + word] = m;
}

__global__ __launch_bounds__(256) void iou3d_row_kernel(
        const float* __restrict__ pred, const float* __restrict__ gt,
        const int* __restrict__ sampled, u64* __restrict__ rowmax) {
    int i = blockIdx.y;
    int j = blockIdx.x * 256 + threadIdx.x;
    float Ax = pred[i * 7 + 0], Ay = pred[i * 7 + 1], Az = pred[i * 7 + 2];
    float Adx = pred[i * 7 + 3], Ady = pred[i * 7 + 4], Adz = pred[i * 7 + 5];
    float Ar = pred[i * 7 + 6];
    float msk = sampled[j] ? 1.0f : 0.0f;
    float Bx = gt[j * 8 + 0] * msk, By = gt[j * 8 + 1] * msk;
    float Bz = gt[j * 8 + 2] * msk;
    float Bdx = gt[j * 8 + 3] * msk, Bdy = gt[j * 8 + 4] * msk;
    float Bdz = gt[j * 8 + 5] * msk;
    float Br = gt[j * 8 + 6] * msk;
    float inter = rect_inter_area(Ax, Ay, Adx, Ady, Ar, Bx, By, Bdx, Bdy, Br);
    float amax = Az + Adz * 0.5f, amin = Az - Adz * 0.5f;
    float bmax = Bz + Bdz * 0.5f, bmin = Bz - Bdz * 0.5f;
    float oh = fmaxf(fminf(amax, bmax) - fmaxf(amin, bmin), 0.0f);
    float inter3d = inter * oh;
    float va = Adx * Ady * Adz, vb = Bdx * Bdy * Bdz;
    float iou = inter3d / fmaxf(va + vb - inter3d, 1e-8f);
    u64 pk = (((u64)__float_as_uint(iou)) << 32) | (u64)(1023 - j);
    atomicMax(&rowmax[i], pk);
}

// ---------------------------------------------------------------------------
// Workspace layout:
//   [0,       4096)    int   order[1024]
//   [4096,    36864)   float sbox[1024*8]
//   [36864,   40960)   int   sampled[1024]
//   [40960,   172032)  u64   sup[1024*16]
//   [172032,  188416)  float4 circ_s[1024]
//   [188416,  204800)  float4 circ_g[1024]
//   [204800,  221184)  float4 circ_p[1024]
//   [221184,  229376)  u64   rowmax[1024]
//   [229376,  229440)  uint  cnt[2] (+pad)
//   [229440, +4*CAP)   uint  listA
//   [+4*CAP, +8*CAP)   uint  listB
// ---------------------------------------------------------------------------
extern "C" void kernel_launch(void* const* d_in, const int* in_sizes, int n_in,
                              void* d_out, int out_size, void* d_ws, size_t ws_size,
                              hipStream_t stream) {
    const float* labels = (const float*)d_in[0];
    const float* pred   = (const float*)d_in[1];
    const float* gt     = (const float*)d_in[2];
    const float* cls    = (const float*)d_in[3];
    float* out = (float*)d_out;

    char* ws = (char*)d_ws;
    int* order   = (int*)ws;
    float* sbox  = (float*)(ws + 4096);
    int* sampled = (int*)(ws + 36864);
    u64* sup     = (u64*)(ws + 40960);
    float4* circ_s = (float4*)(ws + 172032);
    float4* circ_g = (float4*)(ws + 188416);
    float4* circ_p = (float4*)(ws + 204800);
    u64* rowmax  = (u64*)(ws + 221184);
    unsigned int* cnt  = (unsigned int*)(ws + 229376);
    unsigned int* list = (unsigned int*)(ws + 229440);

    const size_t WS_NEEDED = 229440 + (size_t)8 * CAP;

    if (ws_size >= WS_NEEDED) {
        prep2_kernel<<<1, 1024, 0, stream>>>(labels, cls, gt, pred, out, order,
                                             sbox, circ_s, circ_g, circ_p, sup,
                                             rowmax, cnt);
        cand3_kernel<<<CB3, 64, 0, stream>>>(circ_s, circ_s, sampled, 0,
                                             list, &cnt[0]);
        evalA_kernel<<<256, 64, 0, stream>>>(sbox, list, cnt, sup);
        nms_seq4_kernel<<<1, 64, 0, stream>>>(sup, order, sampled);
        cand3_kernel<<<CB3, 64, 0, stream>>>(circ_p, circ_g, sampled, 1,
                                             list + CAP, &cnt[1]);
        evalB_kernel<<<256, 64, 0, stream>>>(pred, gt, list, cnt, rowmax);
        fin_kernel<<<4, 256, 0, stream>>>(rowmax, out);
    } else {
        prep_kernel<<<1, 1024, 0, stream>>>(labels, cls, gt, out, order, sbox);
        sup_kernel<<<dim3(4, 1024), 256, 0, stream>>>(sbox, sup);
        nms_seq4_kernel<<<1, 64, 0, stream>>>(sup, order, sampled);
        iou3d_row_kernel<<<dim3(4, 1024), 256, 0, stream>>>(pred, gt, sampled,
                                                            rowmax);
        fin_kernel<<<4, 256, 0, stream>>>(rowmax, out);
    }
}